// Round 5
// baseline (359.879 us; speedup 1.0000x reference)
//
#include <hip/hip_runtime.h>
#include <hip/hip_bf16.h>

typedef __hip_bfloat16 bf16;
typedef __attribute__((ext_vector_type(8))) short short8v;          // 8 bf16 (4 VGPRs)
typedef __attribute__((ext_vector_type(8))) unsigned short ushort8v;
typedef __attribute__((ext_vector_type(4))) unsigned short ushort4v;
typedef __attribute__((ext_vector_type(4))) float float4v;

__device__ __forceinline__ float bfu2f(unsigned short u) {
    union { unsigned int i; float f; } v; v.i = ((unsigned int)u) << 16; return v.f;
}
__device__ __forceinline__ unsigned short f2bfu_rn(float x) {
    union { float f; unsigned int i; } u; u.f = x;
    unsigned int r = (u.i + 0x7FFFu + ((u.i >> 16) & 1u)) >> 16;
    return (unsigned short)r;
}

// ---------- cast+transpose weights: W[k][n] fp32 -> Wt[n][k] bf16. grid (4,4,4) ----------
__global__ __launch_bounds__(256) void cast_wt(
    const float* __restrict__ Wq, const float* __restrict__ Wk,
    const float* __restrict__ Wv, const float* __restrict__ Wp,
    unsigned short* __restrict__ wt)
{
    __shared__ unsigned short tile[64][72];
    const float* W = (blockIdx.z == 0) ? Wq : (blockIdx.z == 1) ? Wk
                   : (blockIdx.z == 2) ? Wv : Wp;
    unsigned short* WT = wt + (size_t)blockIdx.z * 65536;
    const int t = threadIdx.x;
    const int k0 = blockIdx.x * 64, n0 = blockIdx.y * 64;
    {
        const int r = t >> 2, cseg = (t & 3) * 16;
        const float* src = W + (size_t)(k0 + r) * 256 + n0 + cseg;
        #pragma unroll
        for (int j = 0; j < 16; ++j) tile[r][cseg + j] = f2bfu_rn(src[j]);
    }
    __syncthreads();
    {
        const int ch = t & 63, lq = t >> 6;
        ushort8v o0, o1;
        #pragma unroll
        for (int i = 0; i < 8; ++i) o0[i] = tile[lq * 16 + i][ch];
        #pragma unroll
        for (int i = 0; i < 8; ++i) o1[i] = tile[lq * 16 + 8 + i][ch];
        unsigned short* dst = WT + (size_t)(n0 + ch) * 256 + k0 + lq * 16;
        *(ushort8v*)(dst)     = o0;
        *(ushort8v*)(dst + 8) = o1;
    }
}

// ---------- MFMA projection core: 16 m-rows x 128 n-cols per wave ----------
__device__ __forceinline__ void proj_core(
    const float* __restrict__ aptr, const unsigned short* __restrict__ Wt,
    int nc0, int m16, int quad, float4v acc[8])
{
    #pragma unroll
    for (int i = 0; i < 8; ++i) acc[i] = (float4v){0.f, 0.f, 0.f, 0.f};
    #pragma unroll
    for (int ks = 0; ks < 8; ++ks) {
        float4 a0 = *(const float4*)(aptr + ks * 32);
        float4 a1 = *(const float4*)(aptr + ks * 32 + 4);
        short8v af;
        af[0] = (short)f2bfu_rn(a0.x); af[1] = (short)f2bfu_rn(a0.y);
        af[2] = (short)f2bfu_rn(a0.z); af[3] = (short)f2bfu_rn(a0.w);
        af[4] = (short)f2bfu_rn(a1.x); af[5] = (short)f2bfu_rn(a1.y);
        af[6] = (short)f2bfu_rn(a1.z); af[7] = (short)f2bfu_rn(a1.w);
        #pragma unroll
        for (int i = 0; i < 8; ++i) {
            short8v bfr = *(const short8v*)(Wt + (size_t)(nc0 + i * 16 + m16) * 256 + ks * 32 + quad * 8);
            acc[i] = __builtin_amdgcn_mfma_f32_16x16x32_bf16(af, bfr, acc[i], 0, 0, 0);
        }
    }
}

// ---------- fused q/k/v projections. grid 691: [0,19) q, [19,355) k, [355,691) v ----------
__global__ __launch_bounds__(256) void proj_all(
    const float* __restrict__ q, const float* __restrict__ k, const float* __restrict__ v,
    const unsigned short* __restrict__ wt,
    unsigned short* __restrict__ qb, unsigned short* __restrict__ kb,
    unsigned short* __restrict__ vt)
{
    const int t = threadIdx.x;
    const int wave = t >> 6, lane = t & 63;
    const int m16 = lane & 15, quad = lane >> 4;
    const int msub = (wave & 1) * 16;
    const int nc0 = (wave >> 1) * 128;
    const int bx = blockIdx.x;

    float4v acc[8];
    if (bx < 19) {                       // ---- query -> qb (row-major), M=600
        const int m0 = bx * 32;
        const int arow = min(m0 + msub + m16, 599);
        proj_core(q + (size_t)arow * 256 + quad * 8, wt, nc0, m16, quad, acc);
        #pragma unroll
        for (int i = 0; i < 8; ++i)
            #pragma unroll
            for (int r = 0; r < 4; ++r) {
                int m = m0 + msub + quad * 4 + r;
                if (m < 600)
                    qb[(size_t)m * 256 + nc0 + i * 16 + m16] = f2bfu_rn(acc[i][r]);
            }
    } else if (bx < 355) {               // ---- key -> kb (row-major), M=10752
        const int m0 = (bx - 19) * 32;
        proj_core(k + (size_t)(m0 + msub + m16) * 256 + quad * 8, wt + 65536, nc0, m16, quad, acc);
        #pragma unroll
        for (int i = 0; i < 8; ++i)
            #pragma unroll
            for (int r = 0; r < 4; ++r) {
                int m = m0 + msub + quad * 4 + r;
                kb[(size_t)m * 256 + nc0 + i * 16 + m16] = f2bfu_rn(acc[i][r]);
            }
    } else {                             // ---- value -> vt (transposed), M=10752
        const int m0 = (bx - 355) * 32;
        proj_core(v + (size_t)(m0 + msub + m16) * 256 + quad * 8, wt + 131072, nc0, m16, quad, acc);
        const int bb = (m0 >= 5376) ? 1 : 0;
        const int lcol = m0 - bb * 5376 + msub + quad * 4;
        #pragma unroll
        for (int i = 0; i < 8; ++i) {
            const int ch = nc0 + i * 16 + m16;
            ushort4v p;
            #pragma unroll
            for (int r = 0; r < 4; ++r) p[r] = f2bfu_rn(acc[i][r]);
            *(ushort4v*)(vt + (size_t)(bb * 256 + ch) * 5376 + lcol) = p;
        }
    }
}

// ---------- fused QK + softmax + PV + mask-field fold. wave = head. ----------
// grid 456 = 2b x 12zz x 19nt (448 l per block), XCD-swizzled: each XCD owns 3
// (b,zz) groups (57 blocks) -> k/vt slices (~1.4 MB) L2-resident (R1: 6 MB
// FETCH). vs R1: probs shrunk 236->136 cols (4 chunks of 112 l, single buffer,
// 34.8 KB LDS) -> 3 blocks/CU (launch_bounds(512,6), VGPR<=85 -- R4's spill
// storm came from a 64-VGPR cap; this body needs ~80). Fold reads vectorized
// (b64/head). PV pads chunk to 128 l with -inf cols (exp->0), vt clamped to
// col 440 (in-slice; pad lanes contribute 0).
__global__ __launch_bounds__(512, 6) void attn_fused(
    const unsigned short* __restrict__ qb, const unsigned short* __restrict__ kb,
    const unsigned short* __restrict__ vt,
    const float* __restrict__ W1, const float* __restrict__ b1,
    const float* __restrict__ W2, const float* __restrict__ b2,
    const float* __restrict__ W3, const float* __restrict__ b3,
    const float* __restrict__ Wm,
    float* __restrict__ xbp, float* __restrict__ Sp,
    float* __restrict__ g2, float* __restrict__ g3, float* __restrict__ maskp)
{
    __shared__ unsigned short probs[8][16 * 136];   // 34,816 B
    __shared__ float wTs[3][64];                    // wTs[l][hh*8+hp] = Wl[hp*8+hh]
    __shared__ float blv[3][8], wmv[3][8];

    const int t = threadIdx.x;
    const int wave = t >> 6, lane = t & 63;

    // XCD decode: 456 = 8 * 57; XCD c owns m in [57c, 57c+57) -> 3 (b,zz) groups
    const int i0 = blockIdx.x;
    const int m = (i0 & 7) * 57 + (i0 >> 3);
    const int grp = m / 19, nt = m - grp * 19;
    const int b = grp / 12, zz = grp - b * 12;
    const int n0 = nt * 16;
    const int l0 = zz * 448;

    if (t < 64) {
        const int hp = t >> 3, hh = t & 7;
        wTs[0][hh * 8 + hp] = W1[t];
        wTs[1][hh * 8 + hp] = W2[t];
        wTs[2][hh * 8 + hp] = W3[t];
    }
    if (t >= 64 && t < 72) {
        const int j = t - 64;
        blv[0][j] = b1[j]; blv[1][j] = b2[j]; blv[2][j] = b3[j];
        wmv[0][j] = Wm[j]; wmv[1][j] = Wm[8 + j]; wmv[2][j] = Wm[16 + j];
    }
    {   // pad cols [112,128) of all 128 rows with -inf once (QK writes only [0,112))
        const int row = t >> 2;
        const ushort4v pad4 = {0xFF80u, 0xFF80u, 0xFF80u, 0xFF80u};
        *(ushort4v*)(&probs[0][0] + row * 136 + 112 + (t & 3) * 4) = pad4;
    }

    const int m16 = lane & 15, quad = lane >> 4;
    const int h = wave;                 // wave = head
    const float scale = 0.17677669529663687f;   // 1/sqrt(32)

    const short8v qfrag = *(const short8v*)(qb + (size_t)(b * 300 + min(n0 + m16, 299)) * 256 + h * 32 + quad * 8);
    const unsigned short* kbase = kb + (size_t)(b * 5376 + l0) * 256 + h * 32 + quad * 8;
    const unsigned short* vt0 = vt + (size_t)(b * 256 + h * 32 + m16) * 5376 + l0;
    const unsigned short* vt1 = vt0 + (size_t)16 * 5376;
    unsigned short* const pw = &probs[wave][0];

    float4v c0 = {0.f, 0.f, 0.f, 0.f};
    float4v c1 = {0.f, 0.f, 0.f, 0.f};
    float sm = 0.f;
    const int nl = t >> 5, sub = t & 31, lb = sub * 4;
    const bool fold_act = (sub < 28) && (n0 + nl < 300);
    const size_t bnf = (size_t)(b * 300 + n0 + nl);

    for (int c = 0; c < 4; ++c) {
        // ---- QK chunk c: 7 tiles of 16 l. A = k (m=l), B = q (n=n).
        #pragma unroll
        for (int i = 0; i < 7; ++i) {
            short8v kf = *(const short8v*)(kbase + (size_t)(c * 112 + i * 16 + m16) * 256);
            float4v cc = {0.f, 0.f, 0.f, 0.f};
            cc = __builtin_amdgcn_mfma_f32_16x16x32_bf16(kf, qfrag, cc, 0, 0, 0);
            ushort4v pk;
            #pragma unroll
            for (int r = 0; r < 4; ++r) pk[r] = f2bfu_rn(cc[r] * scale);
            *(ushort4v*)(pw + m16 * 136 + i * 16 + quad * 4) = pk;
        }
        __syncthreads();   // all heads' logits visible (also fences wTs/pad init on c=0)

        // ---- mask-field fold on chunk c: 16 n x 112 l, 4 px/thread, b64 reads
        if (fold_act) {
            const int p = l0 + c * 112 + lb;
            const int lvl = (p >= 4096) + (p >= 5120);
            ushort4v u[8];
            #pragma unroll
            for (int hp = 0; hp < 8; ++hp)
                u[hp] = *(const ushort4v*)(&probs[hp][nl * 136 + lb]);
            float4 o;
            float* op = (float*)&o;
            #pragma unroll
            for (int half = 0; half < 2; ++half) {      // 2 px at a time: small live set
                float sv[2][8];
                #pragma unroll
                for (int pp = 0; pp < 2; ++pp)
                    #pragma unroll
                    for (int hp = 0; hp < 8; ++hp) sv[pp][hp] = bfu2f(u[hp][half * 2 + pp]);
                float f0 = 0.f, f1 = 0.f;
                #pragma unroll
                for (int hh = 0; hh < 8; ++hh) {
                    const float4 wA = *(const float4*)(&wTs[lvl][hh * 8]);
                    const float4 wB = *(const float4*)(&wTs[lvl][hh * 8 + 4]);
                    const float bb_ = blv[lvl][hh], wm_ = wmv[lvl][hh];
                    float a0 = bb_
                        + sv[0][0] * wA.x + sv[0][1] * wA.y + sv[0][2] * wA.z + sv[0][3] * wA.w
                        + sv[0][4] * wB.x + sv[0][5] * wB.y + sv[0][6] * wB.z + sv[0][7] * wB.w;
                    float a1 = bb_
                        + sv[1][0] * wA.x + sv[1][1] * wA.y + sv[1][2] * wA.z + sv[1][3] * wA.w
                        + sv[1][4] * wB.x + sv[1][5] * wB.y + sv[1][6] * wB.z + sv[1][7] * wB.w;
                    f0 += fmaxf(a0, 0.f) * wm_;
                    f1 += fmaxf(a1, 0.f) * wm_;
                }
                op[half * 2]     = f0;
                op[half * 2 + 1] = f1;
            }
            float* dst = (lvl == 0) ? maskp + bnf * 4096 + p
                       : (lvl == 1) ? g2 + bnf * 1024 + (p - 4096)
                       :              g3 + bnf * 256  + (p - 5120);
            *(float4*)dst = o;
        }

        // ---- PV chunk c: 4 K-steps of 32 (cols [112,128) are -inf pad, exp->0)
        #pragma unroll
        for (int step = 0; step < 4; ++step) {
            const int lloc = step * 32 + quad * 8;
            ushort8v ua = *(const ushort8v*)(pw + m16 * 136 + lloc);
            short8v af;
            #pragma unroll
            for (int j = 0; j < 8; ++j) {
                float e = __expf(bfu2f(ua[j]));
                sm += e;
                af[j] = (short)f2bfu_rn(e);
            }
            const int off = min(c * 112 + lloc, 440);   // pad lanes (af=0) clamp in-slice
            short8v bb0 = *(const short8v*)(vt0 + off);
            short8v bb1 = *(const short8v*)(vt1 + off);
            c0 = __builtin_amdgcn_mfma_f32_16x16x32_bf16(af, bb0, c0, 0, 0, 0);
            c1 = __builtin_amdgcn_mfma_f32_16x16x32_bf16(af, bb1, c1, 0, 0, 0);
        }
        if (c < 3) __syncthreads();   // before next QK overwrites probs
    }

    // ---- per-wave (= per-head) direct stores, no cross-wave reduction
    sm += __shfl_xor(sm, 16);
    sm += __shfl_xor(sm, 32);
    float* xplane = xbp + (size_t)zz * 153600;
    float* splane = Sp + (size_t)zz * 4800;
    if (lane < 16 && n0 + lane < 300)
        splane[(size_t)(b * 300 + n0 + lane) * 8 + h] = sm;
    #pragma unroll
    for (int r = 0; r < 4; ++r) {
        const int n = n0 + quad * 4 + r;
        if (n < 300) {
            float* o = xplane + (size_t)(b * 300 + n) * 256 + h * 32 + m16;
            o[0]  = c0[r];
            o[16] = c1[r];
        }
    }
}

// ---------- finish: blocks [0,600) mask combine (bilinear+relu, in-place on
// maskpart), blocks [600,638) output projection (16 rows each, 12-plane sum).
__global__ __launch_bounds__(256) void finish(
    const float* __restrict__ g2, const float* __restrict__ g3,
    const float* __restrict__ xbp, const float* __restrict__ Sp,
    const unsigned short* __restrict__ Wtp,
    const float* __restrict__ bpv, const float* __restrict__ bmp,
    float* __restrict__ out)
{
    const int t = threadIdx.x;
    if (blockIdx.x < 600) {
        __shared__ float gs[1280];      // g2s [0,1024), g3s [1024,1280)
        __shared__ float bms;
        const int bn = blockIdx.x;
        if (t == 0) bms = bmp[0];
        ((float4v*)gs)[t] = ((const float4v*)(g2 + (size_t)bn * 1024))[t];
        if (t < 64) ((float4v*)(gs + 1024))[t] = ((const float4v*)(g3 + (size_t)bn * 256))[t];
        __syncthreads();

        float* mp = out + 153600 + (size_t)bn * 4096;
        #pragma unroll
        for (int it = 0; it < 4; ++it) {
            const int p0 = it * 1024 + t * 4;
            float4v mv = *(const float4v*)(mp + p0);
            float4v res;
            #pragma unroll
            for (int pp = 0; pp < 4; ++pp) {
                const int p = p0 + pp;
                const int Y = p >> 6, X = p & 63;
                float acc = mv[pp] + bms;
                {   // g2 bilinear 32 -> 64
                    float ry = fminf(fmaxf(0.5f * Y - 0.25f, 0.f), 31.f);
                    float rx = fminf(fmaxf(0.5f * X - 0.25f, 0.f), 31.f);
                    int y0 = (int)ry, x0 = (int)rx;
                    int y1 = min(y0 + 1, 31), x1 = min(x0 + 1, 31);
                    float wy = ry - (float)y0, wx = rx - (float)x0;
                    acc += (gs[y0 * 32 + x0] * (1.f - wx) + gs[y0 * 32 + x1] * wx) * (1.f - wy)
                         + (gs[y1 * 32 + x0] * (1.f - wx) + gs[y1 * 32 + x1] * wx) * wy;
                }
                {   // g3 bilinear 16 -> 64
                    float ry = fminf(fmaxf(0.25f * Y - 0.375f, 0.f), 15.f);
                    float rx = fminf(fmaxf(0.25f * X - 0.375f, 0.f), 15.f);
                    int y0 = (int)ry, x0 = (int)rx;
                    int y1 = min(y0 + 1, 15), x1 = min(x0 + 1, 15);
                    float wy = ry - (float)y0, wx = rx - (float)x0;
                    acc += (gs[1024 + y0 * 16 + x0] * (1.f - wx) + gs[1024 + y0 * 16 + x1] * wx) * (1.f - wy)
                         + (gs[1024 + y1 * 16 + x0] * (1.f - wx) + gs[1024 + y1 * 16 + x1] * wx) * wy;
                }
                res[pp] = fmaxf(acc, 0.f);
            }
            *(float4v*)(mp + p0) = res;
        }
    } else {
        // ---- proj_out: 38 blocks x 16 rows; combine 12 zz planes + 1/S
        const int bx = blockIdx.x - 600;
        const int wave = t >> 6, lane = t & 63;
        const int m16 = lane & 15, quad = lane >> 4;
        const int nc0 = wave * 64;
        const int m0 = bx * 16;
        const int arow = min(m0 + m16, 599);
        const float* a0p = xbp + (size_t)arow * 256 + quad * 8;

        float4v acc[4];
        #pragma unroll
        for (int i = 0; i < 4; ++i) acc[i] = (float4v){0.f, 0.f, 0.f, 0.f};

        #pragma unroll
        for (int ks = 0; ks < 8; ++ks) {
            float S = 0.f;
            #pragma unroll
            for (int z = 0; z < 12; ++z) S += Sp[(size_t)z * 4800 + arow * 8 + ks];
            const float rS = 1.0f / S;
            float a[8];
            #pragma unroll
            for (int half = 0; half < 2; ++half) {
                float4v x = {0.f, 0.f, 0.f, 0.f};
                #pragma unroll
                for (int z = 0; z < 12; ++z)
                    x += *(const float4v*)(a0p + (size_t)z * 153600 + ks * 32 + half * 4);
                a[half * 4 + 0] = x[0] * rS;
                a[half * 4 + 1] = x[1] * rS;
                a[half * 4 + 2] = x[2] * rS;
                a[half * 4 + 3] = x[3] * rS;
            }
            short8v af;
            #pragma unroll
            for (int j = 0; j < 8; ++j) af[j] = (short)f2bfu_rn(a[j]);
            #pragma unroll
            for (int i = 0; i < 4; ++i) {
                short8v bfr = *(const short8v*)(Wtp + (size_t)(nc0 + i * 16 + m16) * 256 + ks * 32 + quad * 8);
                acc[i] = __builtin_amdgcn_mfma_f32_16x16x32_bf16(af, bfr, acc[i], 0, 0, 0);
            }
        }

        #pragma unroll
        for (int i = 0; i < 4; ++i) {
            const float bv = bpv[nc0 + i * 16 + m16];
            #pragma unroll
            for (int r = 0; r < 4; ++r) {
                int mm = m0 + quad * 4 + r;
                if (mm < 600)
                    out[(size_t)mm * 256 + nc0 + i * 16 + m16] = acc[i][r] + bv;
            }
        }
    }
}

// ---------- launch ----------
extern "C" void kernel_launch(void* const* d_in, const int* in_sizes, int n_in,
                              void* d_out, int out_size, void* d_ws, size_t ws_size,
                              hipStream_t stream) {
    const float* query = (const float*)d_in[0];
    const float* key   = (const float*)d_in[1];
    const float* value = (const float*)d_in[2];
    const float* Wq = (const float*)d_in[5];
    const float* Wk = (const float*)d_in[6];
    const float* Wv = (const float*)d_in[7];
    const float* Wp = (const float*)d_in[8];
    const float* bp = (const float*)d_in[9];
    const float* W1 = (const float*)d_in[10];
    const float* b1 = (const float*)d_in[11];
    const float* W2 = (const float*)d_in[12];
    const float* b2 = (const float*)d_in[13];
    const float* W3 = (const float*)d_in[14];
    const float* b3 = (const float*)d_in[15];
    const float* Wm = (const float*)d_in[16];
    const float* bm = (const float*)d_in[17];
    float* out = (float*)d_out;

    char* ws = (char*)d_ws;
    unsigned short* wt = (unsigned short*)(ws);       // 524,288 B
    bf16*  qb   = (bf16*) (ws + 524288);              // 307,200 B
    bf16*  kb   = (bf16*) (ws + 831488);              // 5,505,024 B
    bf16*  vt   = (bf16*) (ws + 6336512);             // 5,505,024 B
    float* xbp  = (float*)(ws + 11841536);            // 12*600*256 fp32 = 7,372,800 B
    float* Sp   = (float*)(ws + 19214336);            // 12*4800 fp32    = 230,400 B
    float* g2   = (float*)(ws + 19444736);            // 600*1024 fp32   = 2,457,600 B
    float* g3   = (float*)(ws + 21902336);            // 600*256 fp32    = 614,400 B
    float* maskp = out + 153600;                      // level-1 fold written in-place

    cast_wt<<<dim3(4, 4, 4), 256, 0, stream>>>(Wq, Wk, Wv, Wp, wt);

    proj_all<<<691, 256, 0, stream>>>(query, key, value, wt,
        (unsigned short*)qb, (unsigned short*)kb, (unsigned short*)vt);

    attn_fused<<<456, 512, 0, stream>>>(
        (const unsigned short*)qb, (const unsigned short*)kb, (const unsigned short*)vt,
        W1, b1, W2, b2, W3, b3, Wm, xbp, Sp, g2, g3, maskp);

    finish<<<638, 256, 0, stream>>>(g2, g3, xbp, Sp,
        (const unsigned short*)wt + 196608, bp, bm, out);
}

// Round 6
// 210.429 us; speedup vs baseline: 1.7102x; 1.7102x over previous
//
#include <hip/hip_runtime.h>
#include <hip/hip_bf16.h>

typedef __hip_bfloat16 bf16;
typedef __attribute__((ext_vector_type(8))) short short8v;          // 8 bf16 (4 VGPRs)
typedef __attribute__((ext_vector_type(8))) unsigned short ushort8v;
typedef __attribute__((ext_vector_type(4))) unsigned short ushort4v;
typedef __attribute__((ext_vector_type(4))) float float4v;

__device__ __forceinline__ float bfu2f(unsigned short u) {
    union { unsigned int i; float f; } v; v.i = ((unsigned int)u) << 16; return v.f;
}
__device__ __forceinline__ unsigned short f2bfu_rn(float x) {
    union { float f; unsigned int i; } u; u.f = x;
    unsigned int r = (u.i + 0x7FFFu + ((u.i >> 16) & 1u)) >> 16;
    return (unsigned short)r;
}

// ---------- cast+transpose weights: W[k][n] fp32 -> Wt[n][k] bf16. grid (4,4,4) ----------
__global__ __launch_bounds__(256) void cast_wt(
    const float* __restrict__ Wq, const float* __restrict__ Wk,
    const float* __restrict__ Wv, const float* __restrict__ Wp,
    unsigned short* __restrict__ wt)
{
    __shared__ unsigned short tile[64][72];
    const float* W = (blockIdx.z == 0) ? Wq : (blockIdx.z == 1) ? Wk
                   : (blockIdx.z == 2) ? Wv : Wp;
    unsigned short* WT = wt + (size_t)blockIdx.z * 65536;
    const int t = threadIdx.x;
    const int k0 = blockIdx.x * 64, n0 = blockIdx.y * 64;
    {
        const int r = t >> 2, cseg = (t & 3) * 16;
        const float* src = W + (size_t)(k0 + r) * 256 + n0 + cseg;
        #pragma unroll
        for (int j = 0; j < 16; ++j) tile[r][cseg + j] = f2bfu_rn(src[j]);
    }
    __syncthreads();
    {
        const int ch = t & 63, lq = t >> 6;
        ushort8v o0, o1;
        #pragma unroll
        for (int i = 0; i < 8; ++i) o0[i] = tile[lq * 16 + i][ch];
        #pragma unroll
        for (int i = 0; i < 8; ++i) o1[i] = tile[lq * 16 + 8 + i][ch];
        unsigned short* dst = WT + (size_t)(n0 + ch) * 256 + k0 + lq * 16;
        *(ushort8v*)(dst)     = o0;
        *(ushort8v*)(dst + 8) = o1;
    }
}

// ---------- MFMA projection core: 16 m-rows x 128 n-cols per wave ----------
__device__ __forceinline__ void proj_core(
    const float* __restrict__ aptr, const unsigned short* __restrict__ Wt,
    int nc0, int m16, int quad, float4v acc[8])
{
    #pragma unroll
    for (int i = 0; i < 8; ++i) acc[i] = (float4v){0.f, 0.f, 0.f, 0.f};
    #pragma unroll
    for (int ks = 0; ks < 8; ++ks) {
        float4 a0 = *(const float4*)(aptr + ks * 32);
        float4 a1 = *(const float4*)(aptr + ks * 32 + 4);
        short8v af;
        af[0] = (short)f2bfu_rn(a0.x); af[1] = (short)f2bfu_rn(a0.y);
        af[2] = (short)f2bfu_rn(a0.z); af[3] = (short)f2bfu_rn(a0.w);
        af[4] = (short)f2bfu_rn(a1.x); af[5] = (short)f2bfu_rn(a1.y);
        af[6] = (short)f2bfu_rn(a1.z); af[7] = (short)f2bfu_rn(a1.w);
        #pragma unroll
        for (int i = 0; i < 8; ++i) {
            short8v bfr = *(const short8v*)(Wt + (size_t)(nc0 + i * 16 + m16) * 256 + ks * 32 + quad * 8);
            acc[i] = __builtin_amdgcn_mfma_f32_16x16x32_bf16(af, bfr, acc[i], 0, 0, 0);
        }
    }
}

// ---------- fused q/k/v projections. grid 691: [0,19) q, [19,355) k, [355,691) v ----------
__global__ __launch_bounds__(256) void proj_all(
    const float* __restrict__ q, const float* __restrict__ k, const float* __restrict__ v,
    const unsigned short* __restrict__ wt,
    unsigned short* __restrict__ qb, unsigned short* __restrict__ kb,
    unsigned short* __restrict__ vt)
{
    const int t = threadIdx.x;
    const int wave = t >> 6, lane = t & 63;
    const int m16 = lane & 15, quad = lane >> 4;
    const int msub = (wave & 1) * 16;
    const int nc0 = (wave >> 1) * 128;
    const int bx = blockIdx.x;

    float4v acc[8];
    if (bx < 19) {                       // ---- query -> qb (row-major), M=600
        const int m0 = bx * 32;
        const int arow = min(m0 + msub + m16, 599);
        proj_core(q + (size_t)arow * 256 + quad * 8, wt, nc0, m16, quad, acc);
        #pragma unroll
        for (int i = 0; i < 8; ++i)
            #pragma unroll
            for (int r = 0; r < 4; ++r) {
                int m = m0 + msub + quad * 4 + r;
                if (m < 600)
                    qb[(size_t)m * 256 + nc0 + i * 16 + m16] = f2bfu_rn(acc[i][r]);
            }
    } else if (bx < 355) {               // ---- key -> kb (row-major), M=10752
        const int m0 = (bx - 19) * 32;
        proj_core(k + (size_t)(m0 + msub + m16) * 256 + quad * 8, wt + 65536, nc0, m16, quad, acc);
        #pragma unroll
        for (int i = 0; i < 8; ++i)
            #pragma unroll
            for (int r = 0; r < 4; ++r) {
                int m = m0 + msub + quad * 4 + r;
                kb[(size_t)m * 256 + nc0 + i * 16 + m16] = f2bfu_rn(acc[i][r]);
            }
    } else {                             // ---- value -> vt (transposed), M=10752
        const int m0 = (bx - 355) * 32;
        proj_core(v + (size_t)(m0 + msub + m16) * 256 + quad * 8, wt + 131072, nc0, m16, quad, acc);
        const int bb = (m0 >= 5376) ? 1 : 0;
        const int lcol = m0 - bb * 5376 + msub + quad * 4;
        #pragma unroll
        for (int i = 0; i < 8; ++i) {
            const int ch = nc0 + i * 16 + m16;
            ushort4v p;
            #pragma unroll
            for (int r = 0; r < 4; ++r) p[r] = f2bfu_rn(acc[i][r]);
            *(ushort4v*)(vt + (size_t)(bb * 256 + ch) * 5376 + lcol) = p;
        }
    }
}

// ---------- fused QK + softmax + PV + mask-field fold. wave = head. ----------
// grid 456 = 2b x 12zz x 19nt (448 l per block), XCD-swizzled: each XCD owns 3
// (b,zz) groups (57 blocks) -> k/vt slices (~1.4 MB) L2-resident (R1: 6 MB
// FETCH). 4 chunks of 112 l, single probs buffer (34.8 KB LDS), vectorized
// b64 fold reads, PV padded to 128 l with -inf cols (exp->0), vt clamped to
// col 440 (in-slice; pad lanes contribute 0).
// NOTE: __launch_bounds__ has NO second arg. In this toolchain the second arg
// is min BLOCKS/CU (CUDA semantics): (512,8)->32 VGPR, (512,6)->40, (512,4)->64
// measured -- each caused a scratch-spill storm (R2/R4/R5 regressions, up to
// 460 MB phantom WRITE). Uncapped, this body fits ~80-96 VGPR, zero spill.
__global__ __launch_bounds__(512) void attn_fused(
    const unsigned short* __restrict__ qb, const unsigned short* __restrict__ kb,
    const unsigned short* __restrict__ vt,
    const float* __restrict__ W1, const float* __restrict__ b1,
    const float* __restrict__ W2, const float* __restrict__ b2,
    const float* __restrict__ W3, const float* __restrict__ b3,
    const float* __restrict__ Wm,
    float* __restrict__ xbp, float* __restrict__ Sp,
    float* __restrict__ g2, float* __restrict__ g3, float* __restrict__ maskp)
{
    __shared__ unsigned short probs[8][16 * 136];   // 34,816 B
    __shared__ float wTs[3][64];                    // wTs[l][hh*8+hp] = Wl[hp*8+hh]
    __shared__ float blv[3][8], wmv[3][8];

    const int t = threadIdx.x;
    const int wave = t >> 6, lane = t & 63;

    // XCD decode: 456 = 8 * 57; XCD c owns m in [57c, 57c+57) -> 3 (b,zz) groups
    const int i0 = blockIdx.x;
    const int m = (i0 & 7) * 57 + (i0 >> 3);
    const int grp = m / 19, nt = m - grp * 19;
    const int b = grp / 12, zz = grp - b * 12;
    const int n0 = nt * 16;
    const int l0 = zz * 448;

    if (t < 64) {
        const int hp = t >> 3, hh = t & 7;
        wTs[0][hh * 8 + hp] = W1[t];
        wTs[1][hh * 8 + hp] = W2[t];
        wTs[2][hh * 8 + hp] = W3[t];
    }
    if (t >= 64 && t < 72) {
        const int j = t - 64;
        blv[0][j] = b1[j]; blv[1][j] = b2[j]; blv[2][j] = b3[j];
        wmv[0][j] = Wm[j]; wmv[1][j] = Wm[8 + j]; wmv[2][j] = Wm[16 + j];
    }
    {   // pad cols [112,128) of all 128 rows with -inf once (QK writes only [0,112))
        const int row = t >> 2;
        const ushort4v pad4 = {0xFF80u, 0xFF80u, 0xFF80u, 0xFF80u};
        *(ushort4v*)(&probs[0][0] + row * 136 + 112 + (t & 3) * 4) = pad4;
    }

    const int m16 = lane & 15, quad = lane >> 4;
    const int h = wave;                 // wave = head
    const float scale = 0.17677669529663687f;   // 1/sqrt(32)

    const short8v qfrag = *(const short8v*)(qb + (size_t)(b * 300 + min(n0 + m16, 299)) * 256 + h * 32 + quad * 8);
    const unsigned short* kbase = kb + (size_t)(b * 5376 + l0) * 256 + h * 32 + quad * 8;
    const unsigned short* vt0 = vt + (size_t)(b * 256 + h * 32 + m16) * 5376 + l0;
    const unsigned short* vt1 = vt0 + (size_t)16 * 5376;
    unsigned short* const pw = &probs[wave][0];

    float4v c0 = {0.f, 0.f, 0.f, 0.f};
    float4v c1 = {0.f, 0.f, 0.f, 0.f};
    float sm = 0.f;
    const int nl = t >> 5, sub = t & 31, lb = sub * 4;
    const bool fold_act = (sub < 28) && (n0 + nl < 300);
    const size_t bnf = (size_t)(b * 300 + n0 + nl);

    for (int c = 0; c < 4; ++c) {
        // ---- QK chunk c: 7 tiles of 16 l. A = k (m=l), B = q (n=n).
        #pragma unroll
        for (int i = 0; i < 7; ++i) {
            short8v kf = *(const short8v*)(kbase + (size_t)(c * 112 + i * 16 + m16) * 256);
            float4v cc = {0.f, 0.f, 0.f, 0.f};
            cc = __builtin_amdgcn_mfma_f32_16x16x32_bf16(kf, qfrag, cc, 0, 0, 0);
            ushort4v pk;
            #pragma unroll
            for (int r = 0; r < 4; ++r) pk[r] = f2bfu_rn(cc[r] * scale);
            *(ushort4v*)(pw + m16 * 136 + i * 16 + quad * 4) = pk;
        }
        __syncthreads();   // all heads' logits visible (also fences wTs/pad init on c=0)

        // ---- mask-field fold on chunk c: 16 n x 112 l, 4 px/thread, b64 reads
        if (fold_act) {
            const int p = l0 + c * 112 + lb;
            const int lvl = (p >= 4096) + (p >= 5120);
            ushort4v u[8];
            #pragma unroll
            for (int hp = 0; hp < 8; ++hp)
                u[hp] = *(const ushort4v*)(&probs[hp][nl * 136 + lb]);
            float4 o;
            float* op = (float*)&o;
            #pragma unroll
            for (int half = 0; half < 2; ++half) {      // 2 px at a time: small live set
                float sv[2][8];
                #pragma unroll
                for (int pp = 0; pp < 2; ++pp)
                    #pragma unroll
                    for (int hp = 0; hp < 8; ++hp) sv[pp][hp] = bfu2f(u[hp][half * 2 + pp]);
                float f0 = 0.f, f1 = 0.f;
                #pragma unroll
                for (int hh = 0; hh < 8; ++hh) {
                    const float4 wA = *(const float4*)(&wTs[lvl][hh * 8]);
                    const float4 wB = *(const float4*)(&wTs[lvl][hh * 8 + 4]);
                    const float bb_ = blv[lvl][hh], wm_ = wmv[lvl][hh];
                    float a0 = bb_
                        + sv[0][0] * wA.x + sv[0][1] * wA.y + sv[0][2] * wA.z + sv[0][3] * wA.w
                        + sv[0][4] * wB.x + sv[0][5] * wB.y + sv[0][6] * wB.z + sv[0][7] * wB.w;
                    float a1 = bb_
                        + sv[1][0] * wA.x + sv[1][1] * wA.y + sv[1][2] * wA.z + sv[1][3] * wA.w
                        + sv[1][4] * wB.x + sv[1][5] * wB.y + sv[1][6] * wB.z + sv[1][7] * wB.w;
                    f0 += fmaxf(a0, 0.f) * wm_;
                    f1 += fmaxf(a1, 0.f) * wm_;
                }
                op[half * 2]     = f0;
                op[half * 2 + 1] = f1;
            }
            float* dst = (lvl == 0) ? maskp + bnf * 4096 + p
                       : (lvl == 1) ? g2 + bnf * 1024 + (p - 4096)
                       :              g3 + bnf * 256  + (p - 5120);
            *(float4*)dst = o;
        }

        // ---- PV chunk c: 4 K-steps of 32 (cols [112,128) are -inf pad, exp->0)
        #pragma unroll
        for (int step = 0; step < 4; ++step) {
            const int lloc = step * 32 + quad * 8;
            ushort8v ua = *(const ushort8v*)(pw + m16 * 136 + lloc);
            short8v af;
            #pragma unroll
            for (int j = 0; j < 8; ++j) {
                float e = __expf(bfu2f(ua[j]));
                sm += e;
                af[j] = (short)f2bfu_rn(e);
            }
            const int off = min(c * 112 + lloc, 440);   // pad lanes (af=0) clamp in-slice
            short8v bb0 = *(const short8v*)(vt0 + off);
            short8v bb1 = *(const short8v*)(vt1 + off);
            c0 = __builtin_amdgcn_mfma_f32_16x16x32_bf16(af, bb0, c0, 0, 0, 0);
            c1 = __builtin_amdgcn_mfma_f32_16x16x32_bf16(af, bb1, c1, 0, 0, 0);
        }
        if (c < 3) __syncthreads();   // before next QK overwrites probs
    }

    // ---- per-wave (= per-head) direct stores, no cross-wave reduction
    sm += __shfl_xor(sm, 16);
    sm += __shfl_xor(sm, 32);
    float* xplane = xbp + (size_t)zz * 153600;
    float* splane = Sp + (size_t)zz * 4800;
    if (lane < 16 && n0 + lane < 300)
        splane[(size_t)(b * 300 + n0 + lane) * 8 + h] = sm;
    #pragma unroll
    for (int r = 0; r < 4; ++r) {
        const int n = n0 + quad * 4 + r;
        if (n < 300) {
            float* o = xplane + (size_t)(b * 300 + n) * 256 + h * 32 + m16;
            o[0]  = c0[r];
            o[16] = c1[r];
        }
    }
}

// ---------- finish: blocks [0,600) mask combine (bilinear+relu, in-place on
// maskpart), blocks [600,638) output projection (16 rows each, 12-plane sum).
__global__ __launch_bounds__(256) void finish(
    const float* __restrict__ g2, const float* __restrict__ g3,
    const float* __restrict__ xbp, const float* __restrict__ Sp,
    const unsigned short* __restrict__ Wtp,
    const float* __restrict__ bpv, const float* __restrict__ bmp,
    float* __restrict__ out)
{
    const int t = threadIdx.x;
    if (blockIdx.x < 600) {
        __shared__ float gs[1280];      // g2s [0,1024), g3s [1024,1280)
        __shared__ float bms;
        const int bn = blockIdx.x;
        if (t == 0) bms = bmp[0];
        ((float4v*)gs)[t] = ((const float4v*)(g2 + (size_t)bn * 1024))[t];
        if (t < 64) ((float4v*)(gs + 1024))[t] = ((const float4v*)(g3 + (size_t)bn * 256))[t];
        __syncthreads();

        float* mp = out + 153600 + (size_t)bn * 4096;
        #pragma unroll
        for (int it = 0; it < 4; ++it) {
            const int p0 = it * 1024 + t * 4;
            float4v mv = *(const float4v*)(mp + p0);
            float4v res;
            #pragma unroll
            for (int pp = 0; pp < 4; ++pp) {
                const int p = p0 + pp;
                const int Y = p >> 6, X = p & 63;
                float acc = mv[pp] + bms;
                {   // g2 bilinear 32 -> 64
                    float ry = fminf(fmaxf(0.5f * Y - 0.25f, 0.f), 31.f);
                    float rx = fminf(fmaxf(0.5f * X - 0.25f, 0.f), 31.f);
                    int y0 = (int)ry, x0 = (int)rx;
                    int y1 = min(y0 + 1, 31), x1 = min(x0 + 1, 31);
                    float wy = ry - (float)y0, wx = rx - (float)x0;
                    acc += (gs[y0 * 32 + x0] * (1.f - wx) + gs[y0 * 32 + x1] * wx) * (1.f - wy)
                         + (gs[y1 * 32 + x0] * (1.f - wx) + gs[y1 * 32 + x1] * wx) * wy;
                }
                {   // g3 bilinear 16 -> 64
                    float ry = fminf(fmaxf(0.25f * Y - 0.375f, 0.f), 15.f);
                    float rx = fminf(fmaxf(0.25f * X - 0.375f, 0.f), 15.f);
                    int y0 = (int)ry, x0 = (int)rx;
                    int y1 = min(y0 + 1, 15), x1 = min(x0 + 1, 15);
                    float wy = ry - (float)y0, wx = rx - (float)x0;
                    acc += (gs[1024 + y0 * 16 + x0] * (1.f - wx) + gs[1024 + y0 * 16 + x1] * wx) * (1.f - wy)
                         + (gs[1024 + y1 * 16 + x0] * (1.f - wx) + gs[1024 + y1 * 16 + x1] * wx) * wy;
                }
                res[pp] = fmaxf(acc, 0.f);
            }
            *(float4v*)(mp + p0) = res;
        }
    } else {
        // ---- proj_out: 38 blocks x 16 rows; combine 12 zz planes + 1/S
        const int bx = blockIdx.x - 600;
        const int wave = t >> 6, lane = t & 63;
        const int m16 = lane & 15, quad = lane >> 4;
        const int nc0 = wave * 64;
        const int m0 = bx * 16;
        const int arow = min(m0 + m16, 599);
        const float* a0p = xbp + (size_t)arow * 256 + quad * 8;

        float4v acc[4];
        #pragma unroll
        for (int i = 0; i < 4; ++i) acc[i] = (float4v){0.f, 0.f, 0.f, 0.f};

        #pragma unroll
        for (int ks = 0; ks < 8; ++ks) {
            float S = 0.f;
            #pragma unroll
            for (int z = 0; z < 12; ++z) S += Sp[(size_t)z * 4800 + arow * 8 + ks];
            const float rS = 1.0f / S;
            float a[8];
            #pragma unroll
            for (int half = 0; half < 2; ++half) {
                float4v x = {0.f, 0.f, 0.f, 0.f};
                #pragma unroll
                for (int z = 0; z < 12; ++z)
                    x += *(const float4v*)(a0p + (size_t)z * 153600 + ks * 32 + half * 4);
                a[half * 4 + 0] = x[0] * rS;
                a[half * 4 + 1] = x[1] * rS;
                a[half * 4 + 2] = x[2] * rS;
                a[half * 4 + 3] = x[3] * rS;
            }
            short8v af;
            #pragma unroll
            for (int j = 0; j < 8; ++j) af[j] = (short)f2bfu_rn(a[j]);
            #pragma unroll
            for (int i = 0; i < 4; ++i) {
                short8v bfr = *(const short8v*)(Wtp + (size_t)(nc0 + i * 16 + m16) * 256 + ks * 32 + quad * 8);
                acc[i] = __builtin_amdgcn_mfma_f32_16x16x32_bf16(af, bfr, acc[i], 0, 0, 0);
            }
        }

        #pragma unroll
        for (int i = 0; i < 4; ++i) {
            const float bv = bpv[nc0 + i * 16 + m16];
            #pragma unroll
            for (int r = 0; r < 4; ++r) {
                int mm = m0 + quad * 4 + r;
                if (mm < 600)
                    out[(size_t)mm * 256 + nc0 + i * 16 + m16] = acc[i][r] + bv;
            }
        }
    }
}

// ---------- launch ----------
extern "C" void kernel_launch(void* const* d_in, const int* in_sizes, int n_in,
                              void* d_out, int out_size, void* d_ws, size_t ws_size,
                              hipStream_t stream) {
    const float* query = (const float*)d_in[0];
    const float* key   = (const float*)d_in[1];
    const float* value = (const float*)d_in[2];
    const float* Wq = (const float*)d_in[5];
    const float* Wk = (const float*)d_in[6];
    const float* Wv = (const float*)d_in[7];
    const float* Wp = (const float*)d_in[8];
    const float* bp = (const float*)d_in[9];
    const float* W1 = (const float*)d_in[10];
    const float* b1 = (const float*)d_in[11];
    const float* W2 = (const float*)d_in[12];
    const float* b2 = (const float*)d_in[13];
    const float* W3 = (const float*)d_in[14];
    const float* b3 = (const float*)d_in[15];
    const float* Wm = (const float*)d_in[16];
    const float* bm = (const float*)d_in[17];
    float* out = (float*)d_out;

    char* ws = (char*)d_ws;
    unsigned short* wt = (unsigned short*)(ws);       // 524,288 B
    bf16*  qb   = (bf16*) (ws + 524288);              // 307,200 B
    bf16*  kb   = (bf16*) (ws + 831488);              // 5,505,024 B
    bf16*  vt   = (bf16*) (ws + 6336512);             // 5,505,024 B
    float* xbp  = (float*)(ws + 11841536);            // 12*600*256 fp32 = 7,372,800 B
    float* Sp   = (float*)(ws + 19214336);            // 12*4800 fp32    = 230,400 B
    float* g2   = (float*)(ws + 19444736);            // 600*1024 fp32   = 2,457,600 B
    float* g3   = (float*)(ws + 21902336);            // 600*256 fp32    = 614,400 B
    float* maskp = out + 153600;                      // level-1 fold written in-place

    cast_wt<<<dim3(4, 4, 4), 256, 0, stream>>>(Wq, Wk, Wv, Wp, wt);

    proj_all<<<691, 256, 0, stream>>>(query, key, value, wt,
        (unsigned short*)qb, (unsigned short*)kb, (unsigned short*)vt);

    attn_fused<<<456, 512, 0, stream>>>(
        (const unsigned short*)qb, (const unsigned short*)kb, (const unsigned short*)vt,
        W1, b1, W2, b2, W3, b3, Wm, xbp, Sp, g2, g3, maskp);

    finish<<<638, 256, 0, stream>>>(g2, g3, xbp, Sp,
        (const unsigned short*)wt + 196608, bp, bm, out);
}

// Round 7
// 191.560 us; speedup vs baseline: 1.8787x; 1.0985x over previous
//
#include <hip/hip_runtime.h>
#include <hip/hip_bf16.h>

typedef __hip_bfloat16 bf16;
typedef __attribute__((ext_vector_type(8))) short short8v;          // 8 bf16 (4 VGPRs)
typedef __attribute__((ext_vector_type(8))) unsigned short ushort8v;
typedef __attribute__((ext_vector_type(4))) unsigned short ushort4v;
typedef __attribute__((ext_vector_type(4))) float float4v;

__device__ __forceinline__ float bfu2f(unsigned short u) {
    union { unsigned int i; float f; } v; v.i = ((unsigned int)u) << 16; return v.f;
}
__device__ __forceinline__ unsigned short f2bfu_rn(float x) {
    union { float f; unsigned int i; } u; u.f = x;
    unsigned int r = (u.i + 0x7FFFu + ((u.i >> 16) & 1u)) >> 16;
    return (unsigned short)r;
}

// ---------- cast+transpose weights: W[k][n] fp32 -> Wt[n][k] bf16. grid (4,4,4) ----------
__global__ __launch_bounds__(256) void cast_wt(
    const float* __restrict__ Wq, const float* __restrict__ Wk,
    const float* __restrict__ Wv, const float* __restrict__ Wp,
    unsigned short* __restrict__ wt)
{
    __shared__ unsigned short tile[64][72];
    const float* W = (blockIdx.z == 0) ? Wq : (blockIdx.z == 1) ? Wk
                   : (blockIdx.z == 2) ? Wv : Wp;
    unsigned short* WT = wt + (size_t)blockIdx.z * 65536;
    const int t = threadIdx.x;
    const int k0 = blockIdx.x * 64, n0 = blockIdx.y * 64;
    {
        const int r = t >> 2, cseg = (t & 3) * 16;
        const float* src = W + (size_t)(k0 + r) * 256 + n0 + cseg;
        #pragma unroll
        for (int j = 0; j < 16; ++j) tile[r][cseg + j] = f2bfu_rn(src[j]);
    }
    __syncthreads();
    {
        const int ch = t & 63, lq = t >> 6;
        ushort8v o0, o1;
        #pragma unroll
        for (int i = 0; i < 8; ++i) o0[i] = tile[lq * 16 + i][ch];
        #pragma unroll
        for (int i = 0; i < 8; ++i) o1[i] = tile[lq * 16 + 8 + i][ch];
        unsigned short* dst = WT + (size_t)(n0 + ch) * 256 + k0 + lq * 16;
        *(ushort8v*)(dst)     = o0;
        *(ushort8v*)(dst + 8) = o1;
    }
}

// ---------- MFMA projection core: 16 m-rows x 128 n-cols per wave ----------
__device__ __forceinline__ void proj_core(
    const float* __restrict__ aptr, const unsigned short* __restrict__ Wt,
    int nc0, int m16, int quad, float4v acc[8])
{
    #pragma unroll
    for (int i = 0; i < 8; ++i) acc[i] = (float4v){0.f, 0.f, 0.f, 0.f};
    #pragma unroll
    for (int ks = 0; ks < 8; ++ks) {
        float4 a0 = *(const float4*)(aptr + ks * 32);
        float4 a1 = *(const float4*)(aptr + ks * 32 + 4);
        short8v af;
        af[0] = (short)f2bfu_rn(a0.x); af[1] = (short)f2bfu_rn(a0.y);
        af[2] = (short)f2bfu_rn(a0.z); af[3] = (short)f2bfu_rn(a0.w);
        af[4] = (short)f2bfu_rn(a1.x); af[5] = (short)f2bfu_rn(a1.y);
        af[6] = (short)f2bfu_rn(a1.z); af[7] = (short)f2bfu_rn(a1.w);
        #pragma unroll
        for (int i = 0; i < 8; ++i) {
            short8v bfr = *(const short8v*)(Wt + (size_t)(nc0 + i * 16 + m16) * 256 + ks * 32 + quad * 8);
            acc[i] = __builtin_amdgcn_mfma_f32_16x16x32_bf16(af, bfr, acc[i], 0, 0, 0);
        }
    }
}

// ---------- fused q/k/v projections. grid 691: [0,19) q, [19,355) k, [355,691) v ----------
__global__ __launch_bounds__(256) void proj_all(
    const float* __restrict__ q, const float* __restrict__ k, const float* __restrict__ v,
    const unsigned short* __restrict__ wt,
    unsigned short* __restrict__ qb, unsigned short* __restrict__ kb,
    unsigned short* __restrict__ vt)
{
    const int t = threadIdx.x;
    const int wave = t >> 6, lane = t & 63;
    const int m16 = lane & 15, quad = lane >> 4;
    const int msub = (wave & 1) * 16;
    const int nc0 = (wave >> 1) * 128;
    const int bx = blockIdx.x;

    float4v acc[8];
    if (bx < 19) {                       // ---- query -> qb (row-major), M=600
        const int m0 = bx * 32;
        const int arow = min(m0 + msub + m16, 599);
        proj_core(q + (size_t)arow * 256 + quad * 8, wt, nc0, m16, quad, acc);
        #pragma unroll
        for (int i = 0; i < 8; ++i)
            #pragma unroll
            for (int r = 0; r < 4; ++r) {
                int m = m0 + msub + quad * 4 + r;
                if (m < 600)
                    qb[(size_t)m * 256 + nc0 + i * 16 + m16] = f2bfu_rn(acc[i][r]);
            }
    } else if (bx < 355) {               // ---- key -> kb (row-major), M=10752
        const int m0 = (bx - 19) * 32;
        proj_core(k + (size_t)(m0 + msub + m16) * 256 + quad * 8, wt + 65536, nc0, m16, quad, acc);
        #pragma unroll
        for (int i = 0; i < 8; ++i)
            #pragma unroll
            for (int r = 0; r < 4; ++r) {
                int m = m0 + msub + quad * 4 + r;
                kb[(size_t)m * 256 + nc0 + i * 16 + m16] = f2bfu_rn(acc[i][r]);
            }
    } else {                             // ---- value -> vt (transposed), M=10752
        const int m0 = (bx - 355) * 32;
        proj_core(v + (size_t)(m0 + msub + m16) * 256 + quad * 8, wt + 131072, nc0, m16, quad, acc);
        const int bb = (m0 >= 5376) ? 1 : 0;
        const int lcol = m0 - bb * 5376 + msub + quad * 4;
        #pragma unroll
        for (int i = 0; i < 8; ++i) {
            const int ch = nc0 + i * 16 + m16;
            ushort4v p;
            #pragma unroll
            for (int r = 0; r < 4; ++r) p[r] = f2bfu_rn(acc[i][r]);
            *(ushort4v*)(vt + (size_t)(bb * 256 + ch) * 5376 + lcol) = p;
        }
    }
}

// ---------- fused QK + softmax + PV + mask-field fold. wave = head. ----------
// grid 1600 (pad of 1596 = 2b x 42zz x 19nt), 128 l per block: exactly 8 QK
// tiles + 4 PV steps, no padding, ONE barrier per block. Level uniform per
// block (zz<32 f1, 32..39 f2, else f3). XCD-grouped decode: XCD c owns 200
// consecutive m (consecutive nt share each 64 KB k/vt slice -> per-XCD working
// set ~1.6 MB, L2-resident). 34.8 KB LDS -> 4 blocks/CU; 1600 blocks -> not
// grid-limited (R6's 456-block grid was).
// NOTE: __launch_bounds__ has NO second arg: in this toolchain the 2nd arg is
// min BLOCKS/CU; (512,8) capped VGPR at 32 and caused R2's 366 MB spill storm.
// Uncapped this body fits ~100 VGPR, zero spill (R6 verified the mechanism).
__global__ __launch_bounds__(512) void attn_fused(
    const unsigned short* __restrict__ qb, const unsigned short* __restrict__ kb,
    const unsigned short* __restrict__ vt,
    const float* __restrict__ W1, const float* __restrict__ b1,
    const float* __restrict__ W2, const float* __restrict__ b2,
    const float* __restrict__ W3, const float* __restrict__ b3,
    const float* __restrict__ Wm,
    float* __restrict__ xbp, float* __restrict__ Sp,
    float* __restrict__ g2, float* __restrict__ g3, float* __restrict__ maskp)
{
    __shared__ unsigned short probs[8][16 * 136];   // 34,816 B
    __shared__ float wT[64];                        // wT[hh*8+hp] = Wl[hp*8+hh]
    __shared__ float blv[8], wmv[8];

    const int t = threadIdx.x;
    const int wave = t >> 6, lane = t & 63;

    // XCD-grouped decode: block i0 -> XCD i0&7 owns 200 consecutive m values
    const int i0 = blockIdx.x;
    const int m = (i0 & 7) * 200 + (i0 >> 3);
    if (m >= 1596) return;
    const int grp = m / 19, nt = m - grp * 19;
    const int b = grp / 42, zz = grp - b * 42;
    const int n0 = nt * 16;
    const int l0 = zz * 128;
    const int lvl = (zz >= 32) + (zz >= 40);

    const float* Wl = (lvl == 0) ? W1 : (lvl == 1) ? W2 : W3;
    const float* bl = (lvl == 0) ? b1 : (lvl == 1) ? b2 : b3;
    if (t < 64) wT[t] = Wl[(t & 7) * 8 + (t >> 3)];
    if (t < 8)  { blv[t] = bl[t]; wmv[t] = Wm[lvl * 8 + t]; }

    const int m16 = lane & 15, quad = lane >> 4;
    const int h = wave;                 // wave = head
    const float scale = 0.17677669529663687f;   // 1/sqrt(32)

    const short8v qfrag = *(const short8v*)(qb + (size_t)(b * 300 + min(n0 + m16, 299)) * 256 + h * 32 + quad * 8);
    const unsigned short* kbase = kb + (size_t)(b * 5376 + l0) * 256 + h * 32 + quad * 8;
    const unsigned short* vt0 = vt + (size_t)(b * 256 + h * 32 + m16) * 5376 + l0;
    const unsigned short* vt1 = vt0 + (size_t)16 * 5376;
    unsigned short* const pw = &probs[wave][0];

    // ---- QK: 8 tiles of 16 l. A = k (m=l), B = q (n=n). C: row=l, col=n.
    #pragma unroll
    for (int i = 0; i < 8; ++i) {
        short8v kf = *(const short8v*)(kbase + (size_t)(i * 16 + m16) * 256);
        float4v c = {0.f, 0.f, 0.f, 0.f};
        c = __builtin_amdgcn_mfma_f32_16x16x32_bf16(kf, qfrag, c, 0, 0, 0);
        ushort4v pk;
        #pragma unroll
        for (int r = 0; r < 4; ++r) pk[r] = f2bfu_rn(c[r] * scale);
        *(ushort4v*)(pw + m16 * 136 + i * 16 + quad * 4) = pk;
    }
    __syncthreads();   // all 8 heads' logits visible (also fences wT/blv/wmv)

    // ---- mask-field fold: 16 n x 128 l, 4 px/thread, uniform level, b64 reads
    {
        const int nl = t >> 5;              // 0..15
        const int n = n0 + nl;
        if (n < 300) {
            const int lb = (t & 31) * 4;
            ushort4v u[8];
            #pragma unroll
            for (int hp = 0; hp < 8; ++hp)
                u[hp] = *(const ushort4v*)(&probs[hp][nl * 136 + lb]);
            float4 o;
            float* op = (float*)&o;
            #pragma unroll
            for (int half = 0; half < 2; ++half) {      // 2 px at a time: small live set
                float sv[2][8];
                #pragma unroll
                for (int pp = 0; pp < 2; ++pp)
                    #pragma unroll
                    for (int hp = 0; hp < 8; ++hp) sv[pp][hp] = bfu2f(u[hp][half * 2 + pp]);
                float f0 = 0.f, f1 = 0.f;
                #pragma unroll
                for (int hh = 0; hh < 8; ++hh) {
                    const float4 wA = *(const float4*)(&wT[hh * 8]);
                    const float4 wB = *(const float4*)(&wT[hh * 8 + 4]);
                    const float bb_ = blv[hh], wm_ = wmv[hh];
                    float a0 = bb_
                        + sv[0][0] * wA.x + sv[0][1] * wA.y + sv[0][2] * wA.z + sv[0][3] * wA.w
                        + sv[0][4] * wB.x + sv[0][5] * wB.y + sv[0][6] * wB.z + sv[0][7] * wB.w;
                    float a1 = bb_
                        + sv[1][0] * wA.x + sv[1][1] * wA.y + sv[1][2] * wA.z + sv[1][3] * wA.w
                        + sv[1][4] * wB.x + sv[1][5] * wB.y + sv[1][6] * wB.z + sv[1][7] * wB.w;
                    f0 += fmaxf(a0, 0.f) * wm_;
                    f1 += fmaxf(a1, 0.f) * wm_;
                }
                op[half * 2]     = f0;
                op[half * 2 + 1] = f1;
            }
            const size_t bn = (size_t)(b * 300 + n);
            const int p = l0 + lb;
            float* dst = (lvl == 0) ? maskp + bn * 4096 + p
                       : (lvl == 1) ? g2 + bn * 1024 + (p - 4096)
                       :              g3 + bn * 256  + (p - 5120);
            *(float4*)dst = o;
        }
    }

    // ---- PV: 4 K-steps of 32 l. A[m=n=m16][k=l], exp on read.
    float4v c0 = {0.f, 0.f, 0.f, 0.f};
    float4v c1 = {0.f, 0.f, 0.f, 0.f};
    float sm = 0.f;
    #pragma unroll
    for (int step = 0; step < 4; ++step) {
        const int lloc = step * 32 + quad * 8;
        ushort8v ua = *(const ushort8v*)(pw + m16 * 136 + lloc);
        short8v af;
        #pragma unroll
        for (int j = 0; j < 8; ++j) {
            float e = __expf(bfu2f(ua[j]));
            sm += e;
            af[j] = (short)f2bfu_rn(e);
        }
        short8v bb0 = *(const short8v*)(vt0 + lloc);
        short8v bb1 = *(const short8v*)(vt1 + lloc);
        c0 = __builtin_amdgcn_mfma_f32_16x16x32_bf16(af, bb0, c0, 0, 0, 0);
        c1 = __builtin_amdgcn_mfma_f32_16x16x32_bf16(af, bb1, c1, 0, 0, 0);
    }

    // ---- per-wave (= per-head) direct stores
    sm += __shfl_xor(sm, 16);
    sm += __shfl_xor(sm, 32);
    float* xplane = xbp + (size_t)zz * 153600;
    float* splane = Sp + (size_t)zz * 4800;
    if (lane < 16 && n0 + lane < 300)
        splane[(size_t)(b * 300 + n0 + lane) * 8 + h] = sm;
    #pragma unroll
    for (int r = 0; r < 4; ++r) {
        const int n = n0 + quad * 4 + r;
        if (n < 300) {
            float* o = xplane + (size_t)(b * 300 + n) * 256 + h * 32 + m16;
            o[0]  = c0[r];
            o[16] = c1[r];
        }
    }
}

// ---------- finish: blocks [0,600) mask combine (bilinear+relu, in-place on
// maskpart); blocks [600,755) reduce 42 xbp planes -> xr and Sp -> Sr.
__global__ __launch_bounds__(256) void finish(
    const float* __restrict__ g2, const float* __restrict__ g3,
    const float* __restrict__ xbp, const float* __restrict__ Sp,
    float* __restrict__ xr, float* __restrict__ Sr,
    const float* __restrict__ bmp, float* __restrict__ out)
{
    const int t = threadIdx.x;
    if (blockIdx.x < 600) {
        __shared__ float gs[1280];      // g2s [0,1024), g3s [1024,1280)
        __shared__ float bms;
        const int bn = blockIdx.x;
        if (t == 0) bms = bmp[0];
        ((float4v*)gs)[t] = ((const float4v*)(g2 + (size_t)bn * 1024))[t];
        if (t < 64) ((float4v*)(gs + 1024))[t] = ((const float4v*)(g3 + (size_t)bn * 256))[t];
        __syncthreads();

        float* mp = out + 153600 + (size_t)bn * 4096;
        #pragma unroll
        for (int it = 0; it < 4; ++it) {
            const int p0 = it * 1024 + t * 4;
            float4v mv = *(const float4v*)(mp + p0);
            float4v res;
            #pragma unroll
            for (int pp = 0; pp < 4; ++pp) {
                const int p = p0 + pp;
                const int Y = p >> 6, X = p & 63;
                float acc = mv[pp] + bms;
                {   // g2 bilinear 32 -> 64
                    float ry = fminf(fmaxf(0.5f * Y - 0.25f, 0.f), 31.f);
                    float rx = fminf(fmaxf(0.5f * X - 0.25f, 0.f), 31.f);
                    int y0 = (int)ry, x0 = (int)rx;
                    int y1 = min(y0 + 1, 31), x1 = min(x0 + 1, 31);
                    float wy = ry - (float)y0, wx = rx - (float)x0;
                    acc += (gs[y0 * 32 + x0] * (1.f - wx) + gs[y0 * 32 + x1] * wx) * (1.f - wy)
                         + (gs[y1 * 32 + x0] * (1.f - wx) + gs[y1 * 32 + x1] * wx) * wy;
                }
                {   // g3 bilinear 16 -> 64
                    float ry = fminf(fmaxf(0.25f * Y - 0.375f, 0.f), 15.f);
                    float rx = fminf(fmaxf(0.25f * X - 0.375f, 0.f), 15.f);
                    int y0 = (int)ry, x0 = (int)rx;
                    int y1 = min(y0 + 1, 15), x1 = min(x0 + 1, 15);
                    float wy = ry - (float)y0, wx = rx - (float)x0;
                    acc += (gs[1024 + y0 * 16 + x0] * (1.f - wx) + gs[1024 + y0 * 16 + x1] * wx) * (1.f - wy)
                         + (gs[1024 + y1 * 16 + x0] * (1.f - wx) + gs[1024 + y1 * 16 + x1] * wx) * wy;
                }
                res[pp] = fmaxf(acc, 0.f);
            }
            *(float4v*)(mp + p0) = res;
        }
    } else {
        const int idx = (blockIdx.x - 600) * 256 + t;   // float4 index
        if (idx < 38400) {
            float4v s = {0.f, 0.f, 0.f, 0.f};
            #pragma unroll 7
            for (int z = 0; z < 42; ++z)
                s += *(const float4v*)(xbp + (size_t)z * 153600 + (size_t)idx * 4);
            *(float4v*)(xr + (size_t)idx * 4) = s;
        } else if (idx < 38400 + 1200) {
            const int si = (idx - 38400) * 4;
            float4v s = {0.f, 0.f, 0.f, 0.f};
            #pragma unroll 7
            for (int z = 0; z < 42; ++z)
                s += *(const float4v*)(Sp + (size_t)z * 4800 + si);
            *(float4v*)(Sr + si) = s;
        }
    }
}

// ---------- output projection on reduced plane + 1/S. grid 38, 16 rows ----------
__global__ __launch_bounds__(256) void proj_out(
    const float* __restrict__ xr, const float* __restrict__ Sr,
    const unsigned short* __restrict__ Wtp,
    const float* __restrict__ bpv, float* __restrict__ out)
{
    const int t = threadIdx.x;
    const int wave = t >> 6, lane = t & 63;
    const int m16 = lane & 15, quad = lane >> 4;
    const int nc0 = wave * 64;
    const int m0 = blockIdx.x * 16;
    const int arow = min(m0 + m16, 599);
    const float* a0p = xr + (size_t)arow * 256 + quad * 8;

    float4v acc[4];
    #pragma unroll
    for (int i = 0; i < 4; ++i) acc[i] = (float4v){0.f, 0.f, 0.f, 0.f};

    #pragma unroll
    for (int ks = 0; ks < 8; ++ks) {
        const float rS = 1.0f / Sr[(size_t)arow * 8 + ks];
        float4 x0 = *(const float4*)(a0p + ks * 32);
        float4 x1 = *(const float4*)(a0p + ks * 32 + 4);
        short8v af;
        af[0] = (short)f2bfu_rn(x0.x * rS); af[1] = (short)f2bfu_rn(x0.y * rS);
        af[2] = (short)f2bfu_rn(x0.z * rS); af[3] = (short)f2bfu_rn(x0.w * rS);
        af[4] = (short)f2bfu_rn(x1.x * rS); af[5] = (short)f2bfu_rn(x1.y * rS);
        af[6] = (short)f2bfu_rn(x1.z * rS); af[7] = (short)f2bfu_rn(x1.w * rS);
        #pragma unroll
        for (int i = 0; i < 4; ++i) {
            short8v bfr = *(const short8v*)(Wtp + (size_t)(nc0 + i * 16 + m16) * 256 + ks * 32 + quad * 8);
            acc[i] = __builtin_amdgcn_mfma_f32_16x16x32_bf16(af, bfr, acc[i], 0, 0, 0);
        }
    }

    #pragma unroll
    for (int i = 0; i < 4; ++i) {
        const float bv = bpv[nc0 + i * 16 + m16];
        #pragma unroll
        for (int r = 0; r < 4; ++r) {
            int mm = m0 + quad * 4 + r;
            if (mm < 600)
                out[(size_t)mm * 256 + nc0 + i * 16 + m16] = acc[i][r] + bv;
        }
    }
}

// ---------- launch ----------
extern "C" void kernel_launch(void* const* d_in, const int* in_sizes, int n_in,
                              void* d_out, int out_size, void* d_ws, size_t ws_size,
                              hipStream_t stream) {
    const float* query = (const float*)d_in[0];
    const float* key   = (const float*)d_in[1];
    const float* value = (const float*)d_in[2];
    const float* Wq = (const float*)d_in[5];
    const float* Wk = (const float*)d_in[6];
    const float* Wv = (const float*)d_in[7];
    const float* Wp = (const float*)d_in[8];
    const float* bp = (const float*)d_in[9];
    const float* W1 = (const float*)d_in[10];
    const float* b1 = (const float*)d_in[11];
    const float* W2 = (const float*)d_in[12];
    const float* b2 = (const float*)d_in[13];
    const float* W3 = (const float*)d_in[14];
    const float* b3 = (const float*)d_in[15];
    const float* Wm = (const float*)d_in[16];
    const float* bm = (const float*)d_in[17];
    float* out = (float*)d_out;

    char* ws = (char*)d_ws;
    unsigned short* wt = (unsigned short*)(ws);       // 524,288 B
    bf16*  qb   = (bf16*) (ws + 524288);              // 307,200 B
    bf16*  kb   = (bf16*) (ws + 831488);              // 5,505,024 B
    bf16*  vt   = (bf16*) (ws + 6336512);             // 5,505,024 B
    float* xbp  = (float*)(ws + 11841536);            // 42*600*256 fp32 = 25,804,800 B
    float* Sp   = (float*)(ws + 37646336);            // 42*4800 fp32    = 806,400 B
    float* g2   = (float*)(ws + 38452736);            // 600*1024 fp32   = 2,457,600 B
    float* g3   = (float*)(ws + 40910336);            // 600*256 fp32    = 614,400 B
    float* xr   = (float*)(ws + 41524736);            // 600*256 fp32    = 614,400 B
    float* Sr   = (float*)(ws + 42139136);            // 4800 fp32       = 19,200 B
    float* maskp = out + 153600;                      // level-1 fold written in-place

    cast_wt<<<dim3(4, 4, 4), 256, 0, stream>>>(Wq, Wk, Wv, Wp, wt);

    proj_all<<<691, 256, 0, stream>>>(query, key, value, wt,
        (unsigned short*)qb, (unsigned short*)kb, (unsigned short*)vt);

    attn_fused<<<1600, 512, 0, stream>>>(
        (const unsigned short*)qb, (const unsigned short*)kb, (const unsigned short*)vt,
        W1, b1, W2, b2, W3, b3, Wm, xbp, Sp, g2, g3, maskp);

    finish<<<755, 256, 0, stream>>>(g2, g3, xbp, Sp, xr, Sr, bm, out);

    proj_out<<<38, 256, 0, stream>>>(xr, Sr, (const unsigned short*)wt + 196608, bp, out);
}

// Round 8
// 183.685 us; speedup vs baseline: 1.9592x; 1.0429x over previous
//
#include <hip/hip_runtime.h>
#include <hip/hip_bf16.h>

typedef __hip_bfloat16 bf16;
typedef __attribute__((ext_vector_type(8))) short short8v;          // 8 bf16 (4 VGPRs)
typedef __attribute__((ext_vector_type(8))) unsigned short ushort8v;
typedef __attribute__((ext_vector_type(4))) unsigned short ushort4v;
typedef __attribute__((ext_vector_type(4))) float float4v;

__device__ __forceinline__ float bfu2f(unsigned short u) {
    union { unsigned int i; float f; } v; v.i = ((unsigned int)u) << 16; return v.f;
}
__device__ __forceinline__ unsigned short f2bfu_rn(float x) {
    union { float f; unsigned int i; } u; u.f = x;
    unsigned int r = (u.i + 0x7FFFu + ((u.i >> 16) & 1u)) >> 16;
    return (unsigned short)r;
}

// ---------- cast+transpose weights: W[k][n] fp32 -> Wt[n][k] bf16. grid (4,4,4) ----------
__global__ __launch_bounds__(256) void cast_wt(
    const float* __restrict__ Wq, const float* __restrict__ Wk,
    const float* __restrict__ Wv, const float* __restrict__ Wp,
    unsigned short* __restrict__ wt)
{
    __shared__ unsigned short tile[64][72];
    const float* W = (blockIdx.z == 0) ? Wq : (blockIdx.z == 1) ? Wk
                   : (blockIdx.z == 2) ? Wv : Wp;
    unsigned short* WT = wt + (size_t)blockIdx.z * 65536;
    const int t = threadIdx.x;
    const int k0 = blockIdx.x * 64, n0 = blockIdx.y * 64;
    {
        const int r = t >> 2, cseg = (t & 3) * 16;
        const float* src = W + (size_t)(k0 + r) * 256 + n0 + cseg;
        #pragma unroll
        for (int j = 0; j < 16; ++j) tile[r][cseg + j] = f2bfu_rn(src[j]);
    }
    __syncthreads();
    {
        const int ch = t & 63, lq = t >> 6;
        ushort8v o0, o1;
        #pragma unroll
        for (int i = 0; i < 8; ++i) o0[i] = tile[lq * 16 + i][ch];
        #pragma unroll
        for (int i = 0; i < 8; ++i) o1[i] = tile[lq * 16 + 8 + i][ch];
        unsigned short* dst = WT + (size_t)(n0 + ch) * 256 + k0 + lq * 16;
        *(ushort8v*)(dst)     = o0;
        *(ushort8v*)(dst + 8) = o1;
    }
}

// ---------- MFMA projection core: 16 m-rows x 128 n-cols per wave ----------
__device__ __forceinline__ void proj_core(
    const float* __restrict__ aptr, const unsigned short* __restrict__ Wt,
    int nc0, int m16, int quad, float4v acc[8])
{
    #pragma unroll
    for (int i = 0; i < 8; ++i) acc[i] = (float4v){0.f, 0.f, 0.f, 0.f};
    #pragma unroll
    for (int ks = 0; ks < 8; ++ks) {
        float4 a0 = *(const float4*)(aptr + ks * 32);
        float4 a1 = *(const float4*)(aptr + ks * 32 + 4);
        short8v af;
        af[0] = (short)f2bfu_rn(a0.x); af[1] = (short)f2bfu_rn(a0.y);
        af[2] = (short)f2bfu_rn(a0.z); af[3] = (short)f2bfu_rn(a0.w);
        af[4] = (short)f2bfu_rn(a1.x); af[5] = (short)f2bfu_rn(a1.y);
        af[6] = (short)f2bfu_rn(a1.z); af[7] = (short)f2bfu_rn(a1.w);
        #pragma unroll
        for (int i = 0; i < 8; ++i) {
            short8v bfr = *(const short8v*)(Wt + (size_t)(nc0 + i * 16 + m16) * 256 + ks * 32 + quad * 8);
            acc[i] = __builtin_amdgcn_mfma_f32_16x16x32_bf16(af, bfr, acc[i], 0, 0, 0);
        }
    }
}

// ---------- fused q/k/v projections. grid 691: [0,19) q, [19,355) k, [355,691) v ----
// k output: HEAD-BLOCKED kb2[b][h][l][32] so attn QK loads are 1KB contiguous/instr.
// v output: L-GROUPED vt3[b][h][l/8][32][8] so attn PV loads are full-line 256B segs.
__global__ __launch_bounds__(256) void proj_all(
    const float* __restrict__ q, const float* __restrict__ k, const float* __restrict__ v,
    const unsigned short* __restrict__ wt,
    unsigned short* __restrict__ qb, unsigned short* __restrict__ kb,
    unsigned short* __restrict__ vt)
{
    const int t = threadIdx.x;
    const int wave = t >> 6, lane = t & 63;
    const int m16 = lane & 15, quad = lane >> 4;
    const int msub = (wave & 1) * 16;
    const int nc0 = (wave >> 1) * 128;
    const int bx = blockIdx.x;

    float4v acc[8];
    if (bx < 19) {                       // ---- query -> qb (row-major), M=600
        const int m0 = bx * 32;
        const int arow = min(m0 + msub + m16, 599);
        proj_core(q + (size_t)arow * 256 + quad * 8, wt, nc0, m16, quad, acc);
        #pragma unroll
        for (int i = 0; i < 8; ++i)
            #pragma unroll
            for (int r = 0; r < 4; ++r) {
                int m = m0 + msub + quad * 4 + r;
                if (m < 600)
                    qb[(size_t)m * 256 + nc0 + i * 16 + m16] = f2bfu_rn(acc[i][r]);
            }
    } else if (bx < 355) {               // ---- key -> kb2[b][h][l][32], M=10752
        const int m0 = (bx - 19) * 32;
        proj_core(k + (size_t)(m0 + msub + m16) * 256 + quad * 8, wt + 65536, nc0, m16, quad, acc);
        const int bb = (m0 >= 5376) ? 1 : 0;
        const int lb0 = m0 - bb * 5376 + msub + quad * 4;
        const int hbase = (wave >> 1) * 4;
        #pragma unroll
        for (int i = 0; i < 8; ++i) {
            const int hh = hbase + (i >> 1);
            const int c16 = (i & 1) * 16;
            unsigned short* kdst = kb + ((size_t)(bb * 8 + hh) * 5376 + lb0) * 32 + c16 + m16;
            #pragma unroll
            for (int r = 0; r < 4; ++r)
                kdst[(size_t)r * 32] = f2bfu_rn(acc[i][r]);
        }
    } else {                             // ---- value -> vt3[b][h][l/8][32][8], M=10752
        const int m0 = (bx - 355) * 32;
        proj_core(v + (size_t)(m0 + msub + m16) * 256 + quad * 8, wt + 131072, nc0, m16, quad, acc);
        const int bb = (m0 >= 5376) ? 1 : 0;
        const int lb0 = m0 - bb * 5376 + msub + quad * 4;   // multiple of 4
        const int g0 = lb0 >> 3, e0 = lb0 & 7;              // e0 in {0,4}
        const int hbase = (wave >> 1) * 4;
        #pragma unroll
        for (int i = 0; i < 8; ++i) {
            const int hh = hbase + (i >> 1);
            const int cc = (i & 1) * 16 + m16;
            ushort4v p;
            #pragma unroll
            for (int r = 0; r < 4; ++r) p[r] = f2bfu_rn(acc[i][r]);
            *(ushort4v*)(vt + (((size_t)(bb * 8 + hh) * 672 + g0) * 32 + cc) * 8 + e0) = p;
        }
    }
}

// ---------- fused QK + softmax + PV + mask-field fold. wave = head. ----------
// grid 1600 (pad of 1596 = 2b x 42zz x 19nt), 128 l per block: 8 QK tiles +
// 4 PV steps, ONE barrier. Level uniform per block. XCD-grouped decode keeps
// per-XCD k/vt working set ~1.6 MB L2-resident. COALESCED OPERANDS (R8):
// kb2[b][h][l][32] -> QK wave-instr reads 1024 B contiguous (was 16 partial
// lines at stride 512 B); vt3[b][h][l/8][32][8] -> PV reads aligned 256-B
// full-line segments. Same math as R7, addressing only.
// __launch_bounds__ second arg intentionally absent (it caps VGPRs as min
// BLOCKS/CU in this toolchain -> R2/R4/R5 spill storms).
__global__ __launch_bounds__(512) void attn_fused(
    const unsigned short* __restrict__ qb, const unsigned short* __restrict__ kb,
    const unsigned short* __restrict__ vt,
    const float* __restrict__ W1, const float* __restrict__ b1,
    const float* __restrict__ W2, const float* __restrict__ b2,
    const float* __restrict__ W3, const float* __restrict__ b3,
    const float* __restrict__ Wm,
    float* __restrict__ xbp, float* __restrict__ Sp,
    float* __restrict__ g2, float* __restrict__ g3, float* __restrict__ maskp)
{
    __shared__ unsigned short probs[8][16 * 136];   // 34,816 B
    __shared__ float wT[64];                        // wT[hh*8+hp] = Wl[hp*8+hh]
    __shared__ float blv[8], wmv[8];

    const int t = threadIdx.x;
    const int wave = t >> 6, lane = t & 63;

    // XCD-grouped decode: block i0 -> XCD i0&7 owns 200 consecutive m values
    const int i0 = blockIdx.x;
    const int m = (i0 & 7) * 200 + (i0 >> 3);
    if (m >= 1596) return;
    const int grp = m / 19, nt = m - grp * 19;
    const int b = grp / 42, zz = grp - b * 42;
    const int n0 = nt * 16;
    const int l0 = zz * 128;
    const int lvl = (zz >= 32) + (zz >= 40);

    const float* Wl = (lvl == 0) ? W1 : (lvl == 1) ? W2 : W3;
    const float* bl = (lvl == 0) ? b1 : (lvl == 1) ? b2 : b3;
    if (t < 64) wT[t] = Wl[(t & 7) * 8 + (t >> 3)];
    if (t < 8)  { blv[t] = bl[t]; wmv[t] = Wm[lvl * 8 + t]; }

    const int m16 = lane & 15, quad = lane >> 4;
    const int h = wave;                 // wave = head
    const float scale = 0.17677669529663687f;   // 1/sqrt(32)

    const short8v qfrag = *(const short8v*)(qb + (size_t)(b * 300 + min(n0 + m16, 299)) * 256 + h * 32 + quad * 8);
    const unsigned short* kbase = kb + ((size_t)(b * 8 + h) * 5376 + l0) * 32 + quad * 8;
    const unsigned short* vtb = vt + ((size_t)(b * 8 + h) * 672 + (l0 >> 3)) * 256 + quad * 256 + m16 * 8;
    unsigned short* const pw = &probs[wave][0];

    // ---- QK: 8 tiles of 16 l. A = k (m=l), B = q (n=n). C: row=l, col=n.
    #pragma unroll
    for (int i = 0; i < 8; ++i) {
        short8v kf = *(const short8v*)(kbase + (size_t)(i * 16 + m16) * 32);
        float4v c = {0.f, 0.f, 0.f, 0.f};
        c = __builtin_amdgcn_mfma_f32_16x16x32_bf16(kf, qfrag, c, 0, 0, 0);
        ushort4v pk;
        #pragma unroll
        for (int r = 0; r < 4; ++r) pk[r] = f2bfu_rn(c[r] * scale);
        *(ushort4v*)(pw + m16 * 136 + i * 16 + quad * 4) = pk;
    }
    __syncthreads();   // all 8 heads' logits visible (also fences wT/blv/wmv)

    // ---- mask-field fold: 16 n x 128 l, 4 px/thread, uniform level, b64 reads
    {
        const int nl = t >> 5;              // 0..15
        const int n = n0 + nl;
        if (n < 300) {
            const int lb = (t & 31) * 4;
            ushort4v u[8];
            #pragma unroll
            for (int hp = 0; hp < 8; ++hp)
                u[hp] = *(const ushort4v*)(&probs[hp][nl * 136 + lb]);
            float4 o;
            float* op = (float*)&o;
            #pragma unroll
            for (int half = 0; half < 2; ++half) {      // 2 px at a time: small live set
                float sv[2][8];
                #pragma unroll
                for (int pp = 0; pp < 2; ++pp)
                    #pragma unroll
                    for (int hp = 0; hp < 8; ++hp) sv[pp][hp] = bfu2f(u[hp][half * 2 + pp]);
                float f0 = 0.f, f1 = 0.f;
                #pragma unroll
                for (int hh = 0; hh < 8; ++hh) {
                    const float4 wA = *(const float4*)(&wT[hh * 8]);
                    const float4 wB = *(const float4*)(&wT[hh * 8 + 4]);
                    const float bb_ = blv[hh], wm_ = wmv[hh];
                    float a0 = bb_
                        + sv[0][0] * wA.x + sv[0][1] * wA.y + sv[0][2] * wA.z + sv[0][3] * wA.w
                        + sv[0][4] * wB.x + sv[0][5] * wB.y + sv[0][6] * wB.z + sv[0][7] * wB.w;
                    float a1 = bb_
                        + sv[1][0] * wA.x + sv[1][1] * wA.y + sv[1][2] * wA.z + sv[1][3] * wA.w
                        + sv[1][4] * wB.x + sv[1][5] * wB.y + sv[1][6] * wB.z + sv[1][7] * wB.w;
                    f0 += fmaxf(a0, 0.f) * wm_;
                    f1 += fmaxf(a1, 0.f) * wm_;
                }
                op[half * 2]     = f0;
                op[half * 2 + 1] = f1;
            }
            const size_t bn = (size_t)(b * 300 + n);
            const int p = l0 + lb;
            float* dst = (lvl == 0) ? maskp + bn * 4096 + p
                       : (lvl == 1) ? g2 + bn * 1024 + (p - 4096)
                       :              g3 + bn * 256  + (p - 5120);
            *(float4*)dst = o;
        }
    }

    // ---- PV: 4 K-steps of 32 l. A[m=n=m16][k=l], exp on read.
    float4v c0 = {0.f, 0.f, 0.f, 0.f};
    float4v c1 = {0.f, 0.f, 0.f, 0.f};
    float sm = 0.f;
    #pragma unroll
    for (int step = 0; step < 4; ++step) {
        const int lloc = step * 32 + quad * 8;
        ushort8v ua = *(const ushort8v*)(pw + m16 * 136 + lloc);
        short8v af;
        #pragma unroll
        for (int j = 0; j < 8; ++j) {
            float e = __expf(bfu2f(ua[j]));
            sm += e;
            af[j] = (short)f2bfu_rn(e);
        }
        short8v bb0 = *(const short8v*)(vtb + step * 1024);
        short8v bb1 = *(const short8v*)(vtb + step * 1024 + 128);
        c0 = __builtin_amdgcn_mfma_f32_16x16x32_bf16(af, bb0, c0, 0, 0, 0);
        c1 = __builtin_amdgcn_mfma_f32_16x16x32_bf16(af, bb1, c1, 0, 0, 0);
    }

    // ---- per-wave (= per-head) direct stores
    sm += __shfl_xor(sm, 16);
    sm += __shfl_xor(sm, 32);
    float* xplane = xbp + (size_t)zz * 153600;
    float* splane = Sp + (size_t)zz * 4800;
    if (lane < 16 && n0 + lane < 300)
        splane[(size_t)(b * 300 + n0 + lane) * 8 + h] = sm;
    #pragma unroll
    for (int r = 0; r < 4; ++r) {
        const int n = n0 + quad * 4 + r;
        if (n < 300) {
            float* o = xplane + (size_t)(b * 300 + n) * 256 + h * 32 + m16;
            o[0]  = c0[r];
            o[16] = c1[r];
        }
    }
}

// ---------- finish: blocks [0,600) mask combine (bilinear+relu, in-place on
// maskpart); blocks [600,755) reduce 42 xbp planes -> xr and Sp -> Sr.
__global__ __launch_bounds__(256) void finish(
    const float* __restrict__ g2, const float* __restrict__ g3,
    const float* __restrict__ xbp, const float* __restrict__ Sp,
    float* __restrict__ xr, float* __restrict__ Sr,
    const float* __restrict__ bmp, float* __restrict__ out)
{
    const int t = threadIdx.x;
    if (blockIdx.x < 600) {
        __shared__ float gs[1280];      // g2s [0,1024), g3s [1024,1280)
        __shared__ float bms;
        const int bn = blockIdx.x;
        if (t == 0) bms = bmp[0];
        ((float4v*)gs)[t] = ((const float4v*)(g2 + (size_t)bn * 1024))[t];
        if (t < 64) ((float4v*)(gs + 1024))[t] = ((const float4v*)(g3 + (size_t)bn * 256))[t];
        __syncthreads();

        float* mp = out + 153600 + (size_t)bn * 4096;
        #pragma unroll
        for (int it = 0; it < 4; ++it) {
            const int p0 = it * 1024 + t * 4;
            float4v mv = *(const float4v*)(mp + p0);
            float4v res;
            #pragma unroll
            for (int pp = 0; pp < 4; ++pp) {
                const int p = p0 + pp;
                const int Y = p >> 6, X = p & 63;
                float acc = mv[pp] + bms;
                {   // g2 bilinear 32 -> 64
                    float ry = fminf(fmaxf(0.5f * Y - 0.25f, 0.f), 31.f);
                    float rx = fminf(fmaxf(0.5f * X - 0.25f, 0.f), 31.f);
                    int y0 = (int)ry, x0 = (int)rx;
                    int y1 = min(y0 + 1, 31), x1 = min(x0 + 1, 31);
                    float wy = ry - (float)y0, wx = rx - (float)x0;
                    acc += (gs[y0 * 32 + x0] * (1.f - wx) + gs[y0 * 32 + x1] * wx) * (1.f - wy)
                         + (gs[y1 * 32 + x0] * (1.f - wx) + gs[y1 * 32 + x1] * wx) * wy;
                }
                {   // g3 bilinear 16 -> 64
                    float ry = fminf(fmaxf(0.25f * Y - 0.375f, 0.f), 15.f);
                    float rx = fminf(fmaxf(0.25f * X - 0.375f, 0.f), 15.f);
                    int y0 = (int)ry, x0 = (int)rx;
                    int y1 = min(y0 + 1, 15), x1 = min(x0 + 1, 15);
                    float wy = ry - (float)y0, wx = rx - (float)x0;
                    acc += (gs[1024 + y0 * 16 + x0] * (1.f - wx) + gs[1024 + y0 * 16 + x1] * wx) * (1.f - wy)
                         + (gs[1024 + y1 * 16 + x0] * (1.f - wx) + gs[1024 + y1 * 16 + x1] * wx) * wy;
                }
                res[pp] = fmaxf(acc, 0.f);
            }
            *(float4v*)(mp + p0) = res;
        }
    } else {
        const int idx = (blockIdx.x - 600) * 256 + t;   // float4 index
        if (idx < 38400) {
            float4v s = {0.f, 0.f, 0.f, 0.f};
            #pragma unroll 7
            for (int z = 0; z < 42; ++z)
                s += *(const float4v*)(xbp + (size_t)z * 153600 + (size_t)idx * 4);
            *(float4v*)(xr + (size_t)idx * 4) = s;
        } else if (idx < 38400 + 1200) {
            const int si = (idx - 38400) * 4;
            float4v s = {0.f, 0.f, 0.f, 0.f};
            #pragma unroll 7
            for (int z = 0; z < 42; ++z)
                s += *(const float4v*)(Sp + (size_t)z * 4800 + si);
            *(float4v*)(Sr + si) = s;
        }
    }
}

// ---------- output projection on reduced plane + 1/S. grid 38, 16 rows ----------
__global__ __launch_bounds__(256) void proj_out(
    const float* __restrict__ xr, const float* __restrict__ Sr,
    const unsigned short* __restrict__ Wtp,
    const float* __restrict__ bpv, float* __restrict__ out)
{
    const int t = threadIdx.x;
    const int wave = t >> 6, lane = t & 63;
    const int m16 = lane & 15, quad = lane >> 4;
    const int nc0 = wave * 64;
    const int m0 = blockIdx.x * 16;
    const int arow = min(m0 + m16, 599);
    const float* a0p = xr + (size_t)arow * 256 + quad * 8;

    float4v acc[4];
    #pragma unroll
    for (int i = 0; i < 4; ++i) acc[i] = (float4v){0.f, 0.f, 0.f, 0.f};

    #pragma unroll
    for (int ks = 0; ks < 8; ++ks) {
        const float rS = 1.0f / Sr[(size_t)arow * 8 + ks];
        float4 x0 = *(const float4*)(a0p + ks * 32);
        float4 x1 = *(const float4*)(a0p + ks * 32 + 4);
        short8v af;
        af[0] = (short)f2bfu_rn(x0.x * rS); af[1] = (short)f2bfu_rn(x0.y * rS);
        af[2] = (short)f2bfu_rn(x0.z * rS); af[3] = (short)f2bfu_rn(x0.w * rS);
        af[4] = (short)f2bfu_rn(x1.x * rS); af[5] = (short)f2bfu_rn(x1.y * rS);
        af[6] = (short)f2bfu_rn(x1.z * rS); af[7] = (short)f2bfu_rn(x1.w * rS);
        #pragma unroll
        for (int i = 0; i < 4; ++i) {
            short8v bfr = *(const short8v*)(Wtp + (size_t)(nc0 + i * 16 + m16) * 256 + ks * 32 + quad * 8);
            acc[i] = __builtin_amdgcn_mfma_f32_16x16x32_bf16(af, bfr, acc[i], 0, 0, 0);
        }
    }

    #pragma unroll
    for (int i = 0; i < 4; ++i) {
        const float bv = bpv[nc0 + i * 16 + m16];
        #pragma unroll
        for (int r = 0; r < 4; ++r) {
            int mm = m0 + quad * 4 + r;
            if (mm < 600)
                out[(size_t)mm * 256 + nc0 + i * 16 + m16] = acc[i][r] + bv;
        }
    }
}

// ---------- launch ----------
extern "C" void kernel_launch(void* const* d_in, const int* in_sizes, int n_in,
                              void* d_out, int out_size, void* d_ws, size_t ws_size,
                              hipStream_t stream) {
    const float* query = (const float*)d_in[0];
    const float* key   = (const float*)d_in[1];
    const float* value = (const float*)d_in[2];
    const float* Wq = (const float*)d_in[5];
    const float* Wk = (const float*)d_in[6];
    const float* Wv = (const float*)d_in[7];
    const float* Wp = (const float*)d_in[8];
    const float* bp = (const float*)d_in[9];
    const float* W1 = (const float*)d_in[10];
    const float* b1 = (const float*)d_in[11];
    const float* W2 = (const float*)d_in[12];
    const float* b2 = (const float*)d_in[13];
    const float* W3 = (const float*)d_in[14];
    const float* b3 = (const float*)d_in[15];
    const float* Wm = (const float*)d_in[16];
    const float* bm = (const float*)d_in[17];
    float* out = (float*)d_out;

    char* ws = (char*)d_ws;
    unsigned short* wt = (unsigned short*)(ws);       // 524,288 B
    bf16*  qb   = (bf16*) (ws + 524288);              // 307,200 B
    bf16*  kb   = (bf16*) (ws + 831488);              // kb2[2][8][5376][32] = 5,505,024 B
    bf16*  vt   = (bf16*) (ws + 6336512);             // vt3[2][8][672][32][8] = 5,505,024 B
    float* xbp  = (float*)(ws + 11841536);            // 42*600*256 fp32 = 25,804,800 B
    float* Sp   = (float*)(ws + 37646336);            // 42*4800 fp32    = 806,400 B
    float* g2   = (float*)(ws + 38452736);            // 600*1024 fp32   = 2,457,600 B
    float* g3   = (float*)(ws + 40910336);            // 600*256 fp32    = 614,400 B
    float* xr   = (float*)(ws + 41524736);            // 600*256 fp32    = 614,400 B
    float* Sr   = (float*)(ws + 42139136);            // 4800 fp32       = 19,200 B
    float* maskp = out + 153600;                      // level-1 fold written in-place

    cast_wt<<<dim3(4, 4, 4), 256, 0, stream>>>(Wq, Wk, Wv, Wp, wt);

    proj_all<<<691, 256, 0, stream>>>(query, key, value, wt,
        (unsigned short*)qb, (unsigned short*)kb, (unsigned short*)vt);

    attn_fused<<<1600, 512, 0, stream>>>(
        (const unsigned short*)qb, (const unsigned short*)kb, (const unsigned short*)vt,
        W1, b1, W2, b2, W3, b3, Wm, xbp, Sp, g2, g3, maskp);

    finish<<<755, 256, 0, stream>>>(g2, g3, xbp, Sp, xr, Sr, bm, out);

    proj_out<<<38, 256, 0, stream>>>(xr, Sr, (const unsigned short*)wt + 196608, bp, out);
}

// Round 9
// 179.627 us; speedup vs baseline: 2.0035x; 1.0226x over previous
//
#include <hip/hip_runtime.h>
#include <hip/hip_bf16.h>

typedef __hip_bfloat16 bf16;
typedef __attribute__((ext_vector_type(8))) short short8v;          // 8 bf16 (4 VGPRs)
typedef __attribute__((ext_vector_type(8))) unsigned short ushort8v;
typedef __attribute__((ext_vector_type(4))) unsigned short ushort4v;
typedef __attribute__((ext_vector_type(4))) float float4v;

__device__ __forceinline__ float bfu2f(unsigned short u) {
    union { unsigned int i; float f; } v; v.i = ((unsigned int)u) << 16; return v.f;
}
__device__ __forceinline__ unsigned short f2bfu_rn(float x) {
    union { float f; unsigned int i; } u; u.f = x;
    unsigned int r = (u.i + 0x7FFFu + ((u.i >> 16) & 1u)) >> 16;
    return (unsigned short)r;
}

// ---------- cast+transpose weights: W[k][n] fp32 -> Wt[n][k] bf16. grid (4,4,4) ----------
__global__ __launch_bounds__(256) void cast_wt(
    const float* __restrict__ Wq, const float* __restrict__ Wk,
    const float* __restrict__ Wv, const float* __restrict__ Wp,
    unsigned short* __restrict__ wt)
{
    __shared__ unsigned short tile[64][72];
    const float* W = (blockIdx.z == 0) ? Wq : (blockIdx.z == 1) ? Wk
                   : (blockIdx.z == 2) ? Wv : Wp;
    unsigned short* WT = wt + (size_t)blockIdx.z * 65536;
    const int t = threadIdx.x;
    const int k0 = blockIdx.x * 64, n0 = blockIdx.y * 64;
    {
        const int r = t >> 2, cseg = (t & 3) * 16;
        const float* src = W + (size_t)(k0 + r) * 256 + n0 + cseg;
        #pragma unroll
        for (int j = 0; j < 16; ++j) tile[r][cseg + j] = f2bfu_rn(src[j]);
    }
    __syncthreads();
    {
        const int ch = t & 63, lq = t >> 6;
        ushort8v o0, o1;
        #pragma unroll
        for (int i = 0; i < 8; ++i) o0[i] = tile[lq * 16 + i][ch];
        #pragma unroll
        for (int i = 0; i < 8; ++i) o1[i] = tile[lq * 16 + 8 + i][ch];
        unsigned short* dst = WT + (size_t)(n0 + ch) * 256 + k0 + lq * 16;
        *(ushort8v*)(dst)     = o0;
        *(ushort8v*)(dst + 8) = o1;
    }
}

// ---------- MFMA projection core: 16 m-rows x 128 n-cols per wave ----------
__device__ __forceinline__ void proj_core(
    const float* __restrict__ aptr, const unsigned short* __restrict__ Wt,
    int nc0, int m16, int quad, float4v acc[8])
{
    #pragma unroll
    for (int i = 0; i < 8; ++i) acc[i] = (float4v){0.f, 0.f, 0.f, 0.f};
    #pragma unroll
    for (int ks = 0; ks < 8; ++ks) {
        float4 a0 = *(const float4*)(aptr + ks * 32);
        float4 a1 = *(const float4*)(aptr + ks * 32 + 4);
        short8v af;
        af[0] = (short)f2bfu_rn(a0.x); af[1] = (short)f2bfu_rn(a0.y);
        af[2] = (short)f2bfu_rn(a0.z); af[3] = (short)f2bfu_rn(a0.w);
        af[4] = (short)f2bfu_rn(a1.x); af[5] = (short)f2bfu_rn(a1.y);
        af[6] = (short)f2bfu_rn(a1.z); af[7] = (short)f2bfu_rn(a1.w);
        #pragma unroll
        for (int i = 0; i < 8; ++i) {
            short8v bfr = *(const short8v*)(Wt + (size_t)(nc0 + i * 16 + m16) * 256 + ks * 32 + quad * 8);
            acc[i] = __builtin_amdgcn_mfma_f32_16x16x32_bf16(af, bfr, acc[i], 0, 0, 0);
        }
    }
}

// ---------- fused q/k/v projections. grid 691: [0,19) q, [19,355) k, [355,691) v ----
// k output: HEAD-BLOCKED kb2[b][h][l][32] so attn QK loads are 1KB contiguous/instr.
// v output: L-GROUPED vt3[b][h][l/8][32][8] so attn PV loads are full-line 256B segs.
__global__ __launch_bounds__(256) void proj_all(
    const float* __restrict__ q, const float* __restrict__ k, const float* __restrict__ v,
    const unsigned short* __restrict__ wt,
    unsigned short* __restrict__ qb, unsigned short* __restrict__ kb,
    unsigned short* __restrict__ vt)
{
    const int t = threadIdx.x;
    const int wave = t >> 6, lane = t & 63;
    const int m16 = lane & 15, quad = lane >> 4;
    const int msub = (wave & 1) * 16;
    const int nc0 = (wave >> 1) * 128;
    const int bx = blockIdx.x;

    float4v acc[8];
    if (bx < 19) {                       // ---- query -> qb (row-major), M=600
        const int m0 = bx * 32;
        const int arow = min(m0 + msub + m16, 599);
        proj_core(q + (size_t)arow * 256 + quad * 8, wt, nc0, m16, quad, acc);
        #pragma unroll
        for (int i = 0; i < 8; ++i)
            #pragma unroll
            for (int r = 0; r < 4; ++r) {
                int m = m0 + msub + quad * 4 + r;
                if (m < 600)
                    qb[(size_t)m * 256 + nc0 + i * 16 + m16] = f2bfu_rn(acc[i][r]);
            }
    } else if (bx < 355) {               // ---- key -> kb2[b][h][l][32], M=10752
        const int m0 = (bx - 19) * 32;
        proj_core(k + (size_t)(m0 + msub + m16) * 256 + quad * 8, wt + 65536, nc0, m16, quad, acc);
        const int bb = (m0 >= 5376) ? 1 : 0;
        const int lb0 = m0 - bb * 5376 + msub + quad * 4;
        const int hbase = (wave >> 1) * 4;
        #pragma unroll
        for (int i = 0; i < 8; ++i) {
            const int hh = hbase + (i >> 1);
            const int c16 = (i & 1) * 16;
            unsigned short* kdst = kb + ((size_t)(bb * 8 + hh) * 5376 + lb0) * 32 + c16 + m16;
            #pragma unroll
            for (int r = 0; r < 4; ++r)
                kdst[(size_t)r * 32] = f2bfu_rn(acc[i][r]);
        }
    } else {                             // ---- value -> vt3[b][h][l/8][32][8], M=10752
        const int m0 = (bx - 355) * 32;
        proj_core(v + (size_t)(m0 + msub + m16) * 256 + quad * 8, wt + 131072, nc0, m16, quad, acc);
        const int bb = (m0 >= 5376) ? 1 : 0;
        const int lb0 = m0 - bb * 5376 + msub + quad * 4;   // multiple of 4
        const int g0 = lb0 >> 3, e0 = lb0 & 7;              // e0 in {0,4}
        const int hbase = (wave >> 1) * 4;
        #pragma unroll
        for (int i = 0; i < 8; ++i) {
            const int hh = hbase + (i >> 1);
            const int cc = (i & 1) * 16 + m16;
            ushort4v p;
            #pragma unroll
            for (int r = 0; r < 4; ++r) p[r] = f2bfu_rn(acc[i][r]);
            *(ushort4v*)(vt + (((size_t)(bb * 8 + hh) * 672 + g0) * 32 + cc) * 8 + e0) = p;
        }
    }
}

// ---------- fused QK + softmax + PV + mask-field fold. wave = head. ----------
// grid 1600 (pad of 1596 = 2b x 42zz x 19nt), 128 l per block. Level uniform
// per block. XCD-grouped decode keeps per-XCD k/vt working set ~1.6 MB
// L2-resident. Coalesced operands (R8): kb2[b][h][l][32], vt3[b][h][l/8][32][8].
// R9 ORDERING: vt fragments prefetched into registers FIRST (independent
// loads in flight during QK); PV runs right after QK with NO barrier (it only
// reads this wave's own probs slice); the single barrier sits before the fold
// (which reads all 8 heads). This takes the barrier + fold off the QK->PV
// critical path and overlaps vt latency with QK MFMA.
// __launch_bounds__ second arg intentionally absent (it caps VGPRs as min
// BLOCKS/CU in this toolchain -> R2/R4/R5 spill storms).
__global__ __launch_bounds__(512) void attn_fused(
    const unsigned short* __restrict__ qb, const unsigned short* __restrict__ kb,
    const unsigned short* __restrict__ vt,
    const float* __restrict__ W1, const float* __restrict__ b1,
    const float* __restrict__ W2, const float* __restrict__ b2,
    const float* __restrict__ W3, const float* __restrict__ b3,
    const float* __restrict__ Wm,
    float* __restrict__ xbp, float* __restrict__ Sp,
    float* __restrict__ g2, float* __restrict__ g3, float* __restrict__ maskp)
{
    __shared__ unsigned short probs[8][16 * 136];   // 34,816 B
    __shared__ float wT[64];                        // wT[hh*8+hp] = Wl[hp*8+hh]
    __shared__ float blv[8], wmv[8];

    const int t = threadIdx.x;
    const int wave = t >> 6, lane = t & 63;

    // XCD-grouped decode: block i0 -> XCD i0&7 owns 200 consecutive m values
    const int i0 = blockIdx.x;
    const int m = (i0 & 7) * 200 + (i0 >> 3);
    if (m >= 1596) return;
    const int grp = m / 19, nt = m - grp * 19;
    const int b = grp / 42, zz = grp - b * 42;
    const int n0 = nt * 16;
    const int l0 = zz * 128;
    const int lvl = (zz >= 32) + (zz >= 40);

    const float* Wl = (lvl == 0) ? W1 : (lvl == 1) ? W2 : W3;
    const float* bl = (lvl == 0) ? b1 : (lvl == 1) ? b2 : b3;
    if (t < 64) wT[t] = Wl[(t & 7) * 8 + (t >> 3)];
    if (t < 8)  { blv[t] = bl[t]; wmv[t] = Wm[lvl * 8 + t]; }

    const int m16 = lane & 15, quad = lane >> 4;
    const int h = wave;                 // wave = head
    const float scale = 0.17677669529663687f;   // 1/sqrt(32)

    const unsigned short* kbase = kb + ((size_t)(b * 8 + h) * 5376 + l0) * 32 + quad * 8;
    const unsigned short* vtb = vt + ((size_t)(b * 8 + h) * 672 + (l0 >> 3)) * 256 + quad * 256 + m16 * 8;
    unsigned short* const pw = &probs[wave][0];

    // ---- prefetch: vt fragments (8x short8v, independent) + q fragment
    short8v vb[8];
    #pragma unroll
    for (int s = 0; s < 4; ++s) {
        vb[2 * s]     = *(const short8v*)(vtb + s * 1024);
        vb[2 * s + 1] = *(const short8v*)(vtb + s * 1024 + 128);
    }
    const short8v qfrag = *(const short8v*)(qb + (size_t)(b * 300 + min(n0 + m16, 299)) * 256 + h * 32 + quad * 8);

    // ---- QK: 8 tiles of 16 l. A = k (m=l), B = q (n=n). C: row=l, col=n.
    #pragma unroll
    for (int i = 0; i < 8; ++i) {
        short8v kf = *(const short8v*)(kbase + (size_t)(i * 16 + m16) * 32);
        float4v c = {0.f, 0.f, 0.f, 0.f};
        c = __builtin_amdgcn_mfma_f32_16x16x32_bf16(kf, qfrag, c, 0, 0, 0);
        ushort4v pk;
        #pragma unroll
        for (int r = 0; r < 4; ++r) pk[r] = f2bfu_rn(c[r] * scale);
        *(ushort4v*)(pw + m16 * 136 + i * 16 + quad * 4) = pk;
    }

    // ---- PV immediately (reads ONLY this wave's probs -> no barrier needed)
    float4v c0 = {0.f, 0.f, 0.f, 0.f};
    float4v c1 = {0.f, 0.f, 0.f, 0.f};
    float sm0 = 0.f, sm1 = 0.f;
    #pragma unroll
    for (int step = 0; step < 4; ++step) {
        const int lloc = step * 32 + quad * 8;
        ushort8v ua = *(const ushort8v*)(pw + m16 * 136 + lloc);
        short8v af;
        #pragma unroll
        for (int j = 0; j < 8; ++j) {
            float e = __expf(bfu2f(ua[j]));
            if (j & 1) sm1 += e; else sm0 += e;
            af[j] = (short)f2bfu_rn(e);
        }
        c0 = __builtin_amdgcn_mfma_f32_16x16x32_bf16(af, vb[2 * step],     c0, 0, 0, 0);
        c1 = __builtin_amdgcn_mfma_f32_16x16x32_bf16(af, vb[2 * step + 1], c1, 0, 0, 0);
    }

    // ---- per-wave (= per-head) direct stores
    float sm = sm0 + sm1;
    sm += __shfl_xor(sm, 16);
    sm += __shfl_xor(sm, 32);
    float* xplane = xbp + (size_t)zz * 153600;
    float* splane = Sp + (size_t)zz * 4800;
    if (lane < 16 && n0 + lane < 300)
        splane[(size_t)(b * 300 + n0 + lane) * 8 + h] = sm;
    #pragma unroll
    for (int r = 0; r < 4; ++r) {
        const int n = n0 + quad * 4 + r;
        if (n < 300) {
            float* o = xplane + (size_t)(b * 300 + n) * 256 + h * 32 + m16;
            o[0]  = c0[r];
            o[16] = c1[r];
        }
    }

    __syncthreads();   // all 8 heads' logits visible (also fences wT/blv/wmv)

    // ---- mask-field fold: 16 n x 128 l, 4 px/thread, uniform level, b64 reads
    {
        const int nl = t >> 5;              // 0..15
        const int n = n0 + nl;
        if (n < 300) {
            const int lb = (t & 31) * 4;
            ushort4v u[8];
            #pragma unroll
            for (int hp = 0; hp < 8; ++hp)
                u[hp] = *(const ushort4v*)(&probs[hp][nl * 136 + lb]);
            float4 o;
            float* op = (float*)&o;
            #pragma unroll
            for (int half = 0; half < 2; ++half) {      // 2 px at a time: small live set
                float sv[2][8];
                #pragma unroll
                for (int pp = 0; pp < 2; ++pp)
                    #pragma unroll
                    for (int hp = 0; hp < 8; ++hp) sv[pp][hp] = bfu2f(u[hp][half * 2 + pp]);
                float f0 = 0.f, f1 = 0.f;
                #pragma unroll
                for (int hh = 0; hh < 8; ++hh) {
                    const float4 wA = *(const float4*)(&wT[hh * 8]);
                    const float4 wB = *(const float4*)(&wT[hh * 8 + 4]);
                    const float bb_ = blv[hh], wm_ = wmv[hh];
                    float a0 = bb_
                        + sv[0][0] * wA.x + sv[0][1] * wA.y + sv[0][2] * wA.z + sv[0][3] * wA.w
                        + sv[0][4] * wB.x + sv[0][5] * wB.y + sv[0][6] * wB.z + sv[0][7] * wB.w;
                    float a1 = bb_
                        + sv[1][0] * wA.x + sv[1][1] * wA.y + sv[1][2] * wA.z + sv[1][3] * wA.w
                        + sv[1][4] * wB.x + sv[1][5] * wB.y + sv[1][6] * wB.z + sv[1][7] * wB.w;
                    f0 += fmaxf(a0, 0.f) * wm_;
                    f1 += fmaxf(a1, 0.f) * wm_;
                }
                op[half * 2]     = f0;
                op[half * 2 + 1] = f1;
            }
            const size_t bn = (size_t)(b * 300 + n);
            const int p = l0 + lb;
            float* dst = (lvl == 0) ? maskp + bn * 4096 + p
                       : (lvl == 1) ? g2 + bn * 1024 + (p - 4096)
                       :              g3 + bn * 256  + (p - 5120);
            *(float4*)dst = o;
        }
    }
}

// ---------- finish: blocks [0,600) mask combine (bilinear+relu, in-place on
// maskpart); blocks [600,755) reduce 42 xbp planes -> xr and Sp -> Sr.
__global__ __launch_bounds__(256) void finish(
    const float* __restrict__ g2, const float* __restrict__ g3,
    const float* __restrict__ xbp, const float* __restrict__ Sp,
    float* __restrict__ xr, float* __restrict__ Sr,
    const float* __restrict__ bmp, float* __restrict__ out)
{
    const int t = threadIdx.x;
    if (blockIdx.x < 600) {
        __shared__ float gs[1280];      // g2s [0,1024), g3s [1024,1280)
        __shared__ float bms;
        const int bn = blockIdx.x;
        if (t == 0) bms = bmp[0];
        ((float4v*)gs)[t] = ((const float4v*)(g2 + (size_t)bn * 1024))[t];
        if (t < 64) ((float4v*)(gs + 1024))[t] = ((const float4v*)(g3 + (size_t)bn * 256))[t];
        __syncthreads();

        float* mp = out + 153600 + (size_t)bn * 4096;
        #pragma unroll
        for (int it = 0; it < 4; ++it) {
            const int p0 = it * 1024 + t * 4;
            float4v mv = *(const float4v*)(mp + p0);
            float4v res;
            #pragma unroll
            for (int pp = 0; pp < 4; ++pp) {
                const int p = p0 + pp;
                const int Y = p >> 6, X = p & 63;
                float acc = mv[pp] + bms;
                {   // g2 bilinear 32 -> 64
                    float ry = fminf(fmaxf(0.5f * Y - 0.25f, 0.f), 31.f);
                    float rx = fminf(fmaxf(0.5f * X - 0.25f, 0.f), 31.f);
                    int y0 = (int)ry, x0 = (int)rx;
                    int y1 = min(y0 + 1, 31), x1 = min(x0 + 1, 31);
                    float wy = ry - (float)y0, wx = rx - (float)x0;
                    acc += (gs[y0 * 32 + x0] * (1.f - wx) + gs[y0 * 32 + x1] * wx) * (1.f - wy)
                         + (gs[y1 * 32 + x0] * (1.f - wx) + gs[y1 * 32 + x1] * wx) * wy;
                }
                {   // g3 bilinear 16 -> 64
                    float ry = fminf(fmaxf(0.25f * Y - 0.375f, 0.f), 15.f);
                    float rx = fminf(fmaxf(0.25f * X - 0.375f, 0.f), 15.f);
                    int y0 = (int)ry, x0 = (int)rx;
                    int y1 = min(y0 + 1, 15), x1 = min(x0 + 1, 15);
                    float wy = ry - (float)y0, wx = rx - (float)x0;
                    acc += (gs[1024 + y0 * 16 + x0] * (1.f - wx) + gs[1024 + y0 * 16 + x1] * wx) * (1.f - wy)
                         + (gs[1024 + y1 * 16 + x0] * (1.f - wx) + gs[1024 + y1 * 16 + x1] * wx) * wy;
                }
                res[pp] = fmaxf(acc, 0.f);
            }
            *(float4v*)(mp + p0) = res;
        }
    } else {
        const int idx = (blockIdx.x - 600) * 256 + t;   // float4 index
        if (idx < 38400) {
            float4v s = {0.f, 0.f, 0.f, 0.f};
            #pragma unroll 7
            for (int z = 0; z < 42; ++z)
                s += *(const float4v*)(xbp + (size_t)z * 153600 + (size_t)idx * 4);
            *(float4v*)(xr + (size_t)idx * 4) = s;
        } else if (idx < 38400 + 1200) {
            const int si = (idx - 38400) * 4;
            float4v s = {0.f, 0.f, 0.f, 0.f};
            #pragma unroll 7
            for (int z = 0; z < 42; ++z)
                s += *(const float4v*)(Sp + (size_t)z * 4800 + si);
            *(float4v*)(Sr + si) = s;
        }
    }
}

// ---------- output projection on reduced plane + 1/S. grid 38, 16 rows ----------
__global__ __launch_bounds__(256) void proj_out(
    const float* __restrict__ xr, const float* __restrict__ Sr,
    const unsigned short* __restrict__ Wtp,
    const float* __restrict__ bpv, float* __restrict__ out)
{
    const int t = threadIdx.x;
    const int wave = t >> 6, lane = t & 63;
    const int m16 = lane & 15, quad = lane >> 4;
    const int nc0 = wave * 64;
    const int m0 = blockIdx.x * 16;
    const int arow = min(m0 + m16, 599);
    const float* a0p = xr + (size_t)arow * 256 + quad * 8;

    float4v acc[4];
    #pragma unroll
    for (int i = 0; i < 4; ++i) acc[i] = (float4v){0.f, 0.f, 0.f, 0.f};

    #pragma unroll
    for (int ks = 0; ks < 8; ++ks) {
        const float rS = 1.0f / Sr[(size_t)arow * 8 + ks];
        float4 x0 = *(const float4*)(a0p + ks * 32);
        float4 x1 = *(const float4*)(a0p + ks * 32 + 4);
        short8v af;
        af[0] = (short)f2bfu_rn(x0.x * rS); af[1] = (short)f2bfu_rn(x0.y * rS);
        af[2] = (short)f2bfu_rn(x0.z * rS); af[3] = (short)f2bfu_rn(x0.w * rS);
        af[4] = (short)f2bfu_rn(x1.x * rS); af[5] = (short)f2bfu_rn(x1.y * rS);
        af[6] = (short)f2bfu_rn(x1.z * rS); af[7] = (short)f2bfu_rn(x1.w * rS);
        #pragma unroll
        for (int i = 0; i < 4; ++i) {
            short8v bfr = *(const short8v*)(Wtp + (size_t)(nc0 + i * 16 + m16) * 256 + ks * 32 + quad * 8);
            acc[i] = __builtin_amdgcn_mfma_f32_16x16x32_bf16(af, bfr, acc[i], 0, 0, 0);
        }
    }

    #pragma unroll
    for (int i = 0; i < 4; ++i) {
        const float bv = bpv[nc0 + i * 16 + m16];
        #pragma unroll
        for (int r = 0; r < 4; ++r) {
            int mm = m0 + quad * 4 + r;
            if (mm < 600)
                out[(size_t)mm * 256 + nc0 + i * 16 + m16] = acc[i][r] + bv;
        }
    }
}

// ---------- launch ----------
extern "C" void kernel_launch(void* const* d_in, const int* in_sizes, int n_in,
                              void* d_out, int out_size, void* d_ws, size_t ws_size,
                              hipStream_t stream) {
    const float* query = (const float*)d_in[0];
    const float* key   = (const float*)d_in[1];
    const float* value = (const float*)d_in[2];
    const float* Wq = (const float*)d_in[5];
    const float* Wk = (const float*)d_in[6];
    const float* Wv = (const float*)d_in[7];
    const float* Wp = (const float*)d_in[8];
    const float* bp = (const float*)d_in[9];
    const float* W1 = (const float*)d_in[10];
    const float* b1 = (const float*)d_in[11];
    const float* W2 = (const float*)d_in[12];
    const float* b2 = (const float*)d_in[13];
    const float* W3 = (const float*)d_in[14];
    const float* b3 = (const float*)d_in[15];
    const float* Wm = (const float*)d_in[16];
    const float* bm = (const float*)d_in[17];
    float* out = (float*)d_out;

    char* ws = (char*)d_ws;
    unsigned short* wt = (unsigned short*)(ws);       // 524,288 B
    bf16*  qb   = (bf16*) (ws + 524288);              // 307,200 B
    bf16*  kb   = (bf16*) (ws + 831488);              // kb2[2][8][5376][32] = 5,505,024 B
    bf16*  vt   = (bf16*) (ws + 6336512);             // vt3[2][8][672][32][8] = 5,505,024 B
    float* xbp  = (float*)(ws + 11841536);            // 42*600*256 fp32 = 25,804,800 B
    float* Sp   = (float*)(ws + 37646336);            // 42*4800 fp32    = 806,400 B
    float* g2   = (float*)(ws + 38452736);            // 600*1024 fp32   = 2,457,600 B
    float* g3   = (float*)(ws + 40910336);            // 600*256 fp32    = 614,400 B
    float* xr   = (float*)(ws + 41524736);            // 600*256 fp32    = 614,400 B
    float* Sr   = (float*)(ws + 42139136);            // 4800 fp32       = 19,200 B
    float* maskp = out + 153600;                      // level-1 fold written in-place

    cast_wt<<<dim3(4, 4, 4), 256, 0, stream>>>(Wq, Wk, Wv, Wp, wt);

    proj_all<<<691, 256, 0, stream>>>(query, key, value, wt,
        (unsigned short*)qb, (unsigned short*)kb, (unsigned short*)vt);

    attn_fused<<<1600, 512, 0, stream>>>(
        (const unsigned short*)qb, (const unsigned short*)kb, (const unsigned short*)vt,
        W1, b1, W2, b2, W3, b3, Wm, xbp, Sp, g2, g3, maskp);

    finish<<<755, 256, 0, stream>>>(g2, g3, xbp, Sp, xr, Sr, bm, out);

    proj_out<<<38, 256, 0, stream>>>(xr, Sr, (const unsigned short*)wt + 196608, bp, out);
}